// Round 7
// baseline (835.865 us; speedup 1.0000x reference)
//
#include <hip/hip_runtime.h>
#include <hip/hip_bf16.h>
#include <math.h>

using bf16 = __hip_bfloat16;
typedef __attribute__((ext_vector_type(8))) short short8;
typedef __attribute__((ext_vector_type(4))) short short4v;
typedef __attribute__((ext_vector_type(4))) float floatx4;

#define SEQLEN   2048
#define ROWS     4096      // B*L
#define DMODEL   1024
#define DINNER   2048
#define NHEADS   32
#define HEADDIM  64
#define DSTATE   64
#define CONVDIM  2176
#define DINPROJ  4256
#define NCHUNK   32        // 2048 / 64

__device__ __forceinline__ float b2f(bf16 x) { return __bfloat162float(x); }
__device__ __forceinline__ bf16  f2b(float x) { return __float2bfloat16(x); }
__device__ __forceinline__ float s2f(short s) { union { short s; bf16 b; } u; u.s = s; return b2f(u.b); }
__device__ __forceinline__ short f2s(float f) { union { short s; bf16 b; } u; u.b = f2b(f); return u.s; }

// vectorized 4-wide loads (fp32 / bf16) -> fp32
__device__ __forceinline__ void load4(const float* p, float* v) {
  float4 t = *(const float4*)p; v[0] = t.x; v[1] = t.y; v[2] = t.z; v[3] = t.w;
}
__device__ __forceinline__ void load4(const bf16* p, float* v) {
  short4v t = *(const short4v*)p;
#pragma unroll
  for (int j = 0; j < 4; ++j) v[j] = s2f(t[j]);
}

// ---------------- async global->LDS (16B per lane) ----------------
typedef __attribute__((address_space(1))) void v_as1;
typedef __attribute__((address_space(3))) void v_as3;
__device__ __forceinline__ void gload_lds16(const void* g, void* l) {
  __builtin_amdgcn_global_load_lds((v_as1*)(g), (v_as3*)(l), 16, 0, 0);
}

// ---------------- fp32 -> bf16 conversion (4 elems/thread) ----------------
__global__ void cvt_kernel(const float* __restrict__ in, bf16* __restrict__ out, int n4) {
  int i = blockIdx.x * 256 + threadIdx.x;
  if (i < n4) {
    float4 v = ((const float4*)in)[i];
    union { bf16 h[4]; uint2 u; } r;
    r.h[0] = f2b(v.x); r.h[1] = f2b(v.y); r.h[2] = f2b(v.z); r.h[3] = f2b(v.w);
    ((uint2*)out)[i] = r.u;
  }
}

// ---------------- block reduction (2 values, 256 threads) ----------------
__device__ __forceinline__ void block_reduce_2(float& a, float& b) {
#pragma unroll
  for (int off = 32; off > 0; off >>= 1) {
    a += __shfl_xor(a, off);
    b += __shfl_xor(b, off);
  }
  __shared__ float ra[4], rb[4];
  int w = threadIdx.x >> 6;
  if ((threadIdx.x & 63) == 0) { ra[w] = a; rb[w] = b; }
  __syncthreads();
  a = ra[0] + ra[1] + ra[2] + ra[3];
  b = rb[0] + rb[1] + rb[2] + rb[3];
}

// ---------------- LayerNorm (1024 cols, fp32/bf16 in, bf16 out) ----------------
// G13: one vector load per thread (thread t owns cols 4t..4t+3), vector store.
template<typename TIN>
__global__ void ln_kernel(const TIN* __restrict__ x, const float* __restrict__ w,
                          const float* __restrict__ b, bf16* __restrict__ out)
{
  int row = blockIdx.x;
  int c0  = threadIdx.x * 4;
  float v[4];
  load4(x + (size_t)row * DMODEL + c0, v);
  float s  = v[0] + v[1] + v[2] + v[3];
  float sq = v[0]*v[0] + v[1]*v[1] + v[2]*v[2] + v[3]*v[3];
  block_reduce_2(s, sq);
  float mu  = s * (1.f / DMODEL);
  float var = sq * (1.f / DMODEL) - mu * mu;
  float rs  = rsqrtf(var + 1e-5f);
  float4 wv = *(const float4*)(w + c0);
  float4 bv = *(const float4*)(b + c0);
  union { bf16 h[4]; uint2 u; } r;
  r.h[0] = f2b((v[0] - mu) * rs * wv.x + bv.x);
  r.h[1] = f2b((v[1] - mu) * rs * wv.y + bv.y);
  r.h[2] = f2b((v[2] - mu) * rs * wv.z + bv.z);
  r.h[3] = f2b((v[3] - mu) * rs * wv.w + bv.w);
  *(uint2*)(out + (size_t)row * DMODEL + c0) = r.u;
}

// ---------------- epilogue helper ----------------
// EPI 0: store bf16
// EPI 1: +bias(fp32), exact GELU, store bf16
// EPI 2: +resid(fp32), store bf16
// EPI 3: +bias(fp32) +resid(bf16), store fp32
template<int EPI>
__device__ __forceinline__ void epi_store(float v, size_t off, int col,
                                          const float* bias, const void* resid, void* Cout)
{
  if (EPI == 0) {
    ((bf16*)Cout)[off] = f2b(v);
  } else if (EPI == 1) {
    v += bias[col];
    v = 0.5f * v * (1.f + erff(v * 0.70710678118654752f));
    ((bf16*)Cout)[off] = f2b(v);
  } else if (EPI == 2) {
    v += ((const float*)resid)[off];
    ((bf16*)Cout)[off] = f2b(v);
  } else {
    v += bias[col] + b2f(((const bf16*)resid)[off]);
    ((float*)Cout)[off] = v;
  }
}

// XOR-swizzle: LDS slot (row, blk16) holds global block (blk16 ^ (row&7)).
// Staging keeps global_load_lds's contiguous lane->LDS mapping; readers XOR too.
//
// GEMM history (R0-R6, frozen lessons):
//  - sync-structure edits on the 128x128 kernel all lost (64KB dbuf -> occupancy
//    crash; BK=32 dbuf -> bank conflicts + 2x barrier rate). R4's "gemm_bt=72.8"
//    was an anomaly — R6 shows it <52.8 with identical code (rule #19 variance).
//  - the K=1024 GEMMs were stuck at 2 blocks/CU = 2 waves/SIMD: barrier drains
//    exposed. Fix is GEOMETRY, not sync: 256x128 tile, 512 threads, 48 KB LDS
//    -> 3 blocks/CU = 6 waves/SIMD (3x wave count for the m114 implicit-overlap
//    mechanism), per-wave math IDENTICAL to the proven 64x64-subtile form.
//  - 64x64 2-phase counted-vmcnt stays for the N=1024 GEMMs (only consistent winner).

// ---------------- GEMM 256x128 tile, 512 thr, single-buffer BK=64 ----------------
template<int EPI>
__global__ __launch_bounds__(512, 6)
void gemm_bt_256128(const bf16* __restrict__ A, const bf16* __restrict__ W,
                    const float* __restrict__ bias, const void* __restrict__ resid,
                    void* __restrict__ Cout, int M, int N, int K)
{
  __shared__ __align__(16) short Asl[256 * 64];   // 32 KB
  __shared__ __align__(16) short Bsl[128 * 64];   // 16 KB -> 48 KB total, 3 blocks/CU
  const int tid  = threadIdx.x;
  const int lane = tid & 63;
  const int wv   = tid >> 6;          // 0..7
  const int wm   = wv >> 1;           // 0..3 : wave owns A rows wm*64..+63
  const int wn   = wv & 1;            // 0..1 : wave owns B rows wn*64..+63
  const int r16  = lane & 15, q = lane >> 4;
  const int m0   = blockIdx.x * 256;  // x = M-tile: XCD affinity on A rows
  const int n0   = blockIdx.y * 128;

  floatx4 acc[4][4] = {};

  for (int k0 = 0; k0 < K; k0 += 64) {
#pragma unroll
    for (int it = 0; it < 4; ++it) {
      int idx = it * 512 + tid;                   // 0..2047
      int row = idx >> 3;                         // 0..255
      int cb  = (((idx & 7) ^ (row & 7)) << 3);   // swizzled source block
      gload_lds16(A + (size_t)(m0 + row) * K + k0 + cb, &Asl[idx * 8]);
    }
#pragma unroll
    for (int it = 0; it < 2; ++it) {
      int idx = it * 512 + tid;                   // 0..1023
      int row = idx >> 3;                         // 0..127
      int grow = n0 + row; if (grow > N - 1) grow = N - 1;   // N-guard (in_proj N=4256)
      int cb  = (((idx & 7) ^ (row & 7)) << 3);
      gload_lds16(W + (size_t)grow * K + k0 + cb, &Bsl[idx * 8]);
    }
    __syncthreads();
#pragma unroll
    for (int kk = 0; kk < 64; kk += 32) {
      short8 af[4], bfr[4];
      const int lb = (kk >> 3) + q;               // logical 16B block 0..7
#pragma unroll
      for (int i = 0; i < 4; ++i) {
        int ar = wm * 64 + i * 16 + r16;
        af[i] = *(const short8*)&Asl[ar * 64 + ((lb ^ (ar & 7)) << 3)];
      }
#pragma unroll
      for (int j = 0; j < 4; ++j) {
        int br = wn * 64 + j * 16 + r16;
        bfr[j] = *(const short8*)&Bsl[br * 64 + ((lb ^ (br & 7)) << 3)];
      }
#pragma unroll
      for (int i = 0; i < 4; ++i)
#pragma unroll
        for (int j = 0; j < 4; ++j)
          acc[i][j] = __builtin_amdgcn_mfma_f32_16x16x32_bf16(af[i], bfr[j], acc[i][j], 0, 0, 0);
    }
    __syncthreads();
  }

#pragma unroll
  for (int i = 0; i < 4; ++i)
#pragma unroll
    for (int j = 0; j < 4; ++j)
#pragma unroll
      for (int r = 0; r < 4; ++r) {
        int row = m0 + wm * 64 + i * 16 + q * 4 + r;
        int col = n0 + wn * 64 + j * 16 + r16;
        if (col < N)
          epi_store<EPI>(acc[i][j][r], (size_t)row * N + col, col, bias, resid, Cout);
      }
}

// ---------------- GEMM 64x64 tile (N=1024 GEMMs): 1024 blocks = 4/CU, 32 KB LDS ----------------
// 2-phase pipeline: stage tile t+1 into buf^1 BEFORE computing tile t; counted
// vmcnt(4) drains only tile t's loads while t+1's stay in flight across the barrier.
template<int EPI>
__global__ __launch_bounds__(256, 4)
void gemm_bt_6464(const bf16* __restrict__ A, const bf16* __restrict__ W,
                  const float* __restrict__ bias, const void* __restrict__ resid,
                  void* __restrict__ Cout, int M, int N, int K)
{
  __shared__ __align__(16) short Asl[2][64 * 64];    // 2 x 8 KB
  __shared__ __align__(16) short Bsl[2][64 * 64];    // 2 x 8 KB
  const int tid  = threadIdx.x;
  const int lane = tid & 63;
  const int wv   = tid >> 6;
  const int wm   = wv >> 1, wn = wv & 1;          // 2x2 wave grid of 32x32 sub-tiles
  const int r16  = lane & 15, q = lane >> 4;
  const int m0   = blockIdx.x * 64;               // x = M-tile: XCD pin on A rows
  const int n0   = blockIdx.y * 64;

  floatx4 acc[2][2] = {};

  auto stage = [&](int b, int k0) {
#pragma unroll
    for (int it = 0; it < 2; ++it) {
      int idx = it * 256 + tid;
      int cb  = (((idx & 7) ^ ((idx >> 3) & 7)) << 3);
      gload_lds16(A + (size_t)(m0 + (idx >> 3)) * K + k0 + cb, &Asl[b][idx * 8]);
    }
#pragma unroll
    for (int it = 0; it < 2; ++it) {
      int idx = it * 256 + tid;
      int cb  = (((idx & 7) ^ ((idx >> 3) & 7)) << 3);
      gload_lds16(W + (size_t)(n0 + (idx >> 3)) * K + k0 + cb, &Bsl[b][idx * 8]);
    }
  };
  auto compute = [&](int b) {
#pragma unroll
    for (int kk = 0; kk < 64; kk += 32) {
      short8 af[2], bfr[2];
      const int lb = (kk >> 3) + q;
#pragma unroll
      for (int i = 0; i < 2; ++i) {
        int ar = wm * 32 + i * 16 + r16;
        af[i] = *(const short8*)&Asl[b][ar * 64 + ((lb ^ (ar & 7)) << 3)];
      }
#pragma unroll
      for (int j = 0; j < 2; ++j) {
        int br = wn * 32 + j * 16 + r16;
        bfr[j] = *(const short8*)&Bsl[b][br * 64 + ((lb ^ (br & 7)) << 3)];
      }
#pragma unroll
      for (int i = 0; i < 2; ++i)
#pragma unroll
        for (int j = 0; j < 2; ++j)
          acc[i][j] = __builtin_amdgcn_mfma_f32_16x16x32_bf16(af[i], bfr[j], acc[i][j], 0, 0, 0);
    }
  };

  stage(0, 0);
  const int nt = K >> 6;
  int cur = 0;
  for (int t = 0; t < nt - 1; ++t) {
    stage(cur ^ 1, (t + 1) << 6);                 // 4 loads/thread in flight
    asm volatile("s_waitcnt vmcnt(4)" ::: "memory");   // drain tile t only
    __builtin_amdgcn_s_barrier();
    compute(cur);
    asm volatile("s_waitcnt lgkmcnt(0)" ::: "memory");
    __builtin_amdgcn_s_barrier();
    cur ^= 1;
  }
  asm volatile("s_waitcnt vmcnt(0)" ::: "memory");
  __builtin_amdgcn_s_barrier();
  compute(cur);

#pragma unroll
  for (int i = 0; i < 2; ++i)
#pragma unroll
    for (int j = 0; j < 2; ++j)
#pragma unroll
      for (int r = 0; r < 4; ++r) {
        int row = m0 + wm * 32 + i * 16 + q * 4 + r;
        int col = n0 + wn * 32 + j * 16 + r16;
        epi_store<EPI>(acc[i][j][r], (size_t)row * N + col, col, bias, resid, Cout);
      }
}

// ---------------- depthwise causal conv (4 tap) + SiLU + softplus(dt) ----------------
// G13: 8-contiguous-channel groups per thread -> 4x short8 tap loads + 8x float4
// weight loads + short8 stores.
__global__ void conv_kernel(const bf16* __restrict__ zx, const float* __restrict__ cw,
                            const float* __restrict__ cb, const float* __restrict__ dtbias,
                            bf16* __restrict__ xbc, bf16* __restrict__ Bb,
                            bf16* __restrict__ Cbb, float* __restrict__ dtb)
{
  int row = blockIdx.x;
  int b = row >> 11, t = row & 2047;
  const size_t rowbase = (size_t)(b * SEQLEN) * DINPROJ + DINNER;
  for (int c8 = threadIdx.x; c8 < CONVDIM / 8; c8 += 256) {
    int c = c8 * 8;
    float acc[8];
    {
      float4 b0 = *(const float4*)(cb + c);
      float4 b1 = *(const float4*)(cb + c + 4);
      acc[0] = b0.x; acc[1] = b0.y; acc[2] = b0.z; acc[3] = b0.w;
      acc[4] = b1.x; acc[5] = b1.y; acc[6] = b1.z; acc[7] = b1.w;
    }
    float4 wj[8];
#pragma unroll
    for (int j = 0; j < 8; ++j) wj[j] = *(const float4*)(cw + (c + j) * 4);
    short8 xv[4];
#pragma unroll
    for (int k = 0; k < 4; ++k) {
      int tt = t + k - 3;
      if (tt >= 0) {
        xv[k] = *(const short8*)(zx + rowbase + (size_t)tt * DINPROJ + c);
#pragma unroll
        for (int j = 0; j < 8; ++j) {
          float wk = (k == 0) ? wj[j].x : (k == 1) ? wj[j].y : (k == 2) ? wj[j].z : wj[j].w;
          acc[j] += s2f(xv[k][j]) * wk;
        }
      }
    }
    short8 outv;
#pragma unroll
    for (int j = 0; j < 8; ++j) {
      float s = acc[j] / (1.f + __expf(-acc[j]));   // SiLU
      outv[j] = f2s(s);
    }
    *(short8*)(xbc + (size_t)row * CONVDIM + c) = outv;
    if (c >= DINNER) {
      if (c < DINNER + DSTATE) *(short8*)(Bb + row * DSTATE + (c - DINNER)) = outv;
      else                     *(short8*)(Cbb + row * DSTATE + (c - DINNER - DSTATE)) = outv;
    }
  }
  if (threadIdx.x < NHEADS) {
    int hh = threadIdx.x;
    float raw = b2f(zx[(size_t)row * DINPROJ + DINNER + CONVDIM + hh]) + dtbias[hh];
    float dt = raw > 20.f ? raw : log1pf(__expf(raw));   // softplus
    dtb[row * NHEADS + hh] = dt;
  }
}

// ---------------- wave inclusive prefix sum helper ----------------
__device__ __forceinline__ float wave_incl_prefix(float a, int lane) {
#pragma unroll
  for (int off = 1; off < 64; off <<= 1) {
    float o = __shfl_up(a, off);
    if (lane >= off) a += o;
  }
  return a;
}

// ---------------- SSD phase A: chunk end-state S = Xw^T @ B, decay P ----------------
__global__ __launch_bounds__(64)
void chunk_state_kernel(const bf16* __restrict__ xbc, const bf16* __restrict__ Bb,
                        const float* __restrict__ dtb, const float* __restrict__ A_log,
                        float* __restrict__ Sbuf, float* __restrict__ Pbuf)
{
  const int blk = blockIdx.x;
  const int c = blk & 31, h = (blk >> 5) & 31, b = blk >> 10;
  const int bh = b * 32 + h;
  const int lane = threadIdx.x;              // = s (timestep within chunk)
  const int row = b * SEQLEN + c * 64 + lane;
  const float Ah = -__expf(A_log[h]);

  float dts = dtb[row * NHEADS + h];
  float E = wave_incl_prefix(dts * Ah, lane);
  float EQ = __shfl(E, 63);
  float w = __expf(EQ - E) * dts;
  if (lane == 63) Pbuf[bh * NCHUNK + c] = __expf(EQ);

  __shared__ __align__(16) short XwT[64 * 72];   // [p][s] pad 72
  __shared__ __align__(16) short BT[64 * 72];    // [n][s] pad 72

  const bf16* xrow = xbc + (size_t)row * CONVDIM + h * 64;
  const bf16* brow = Bb + (size_t)row * DSTATE;
#pragma unroll
  for (int i = 0; i < 8; ++i) {
    short8 xv = *(const short8*)(xrow + i * 8);
    short8 bv = *(const short8*)(brow + i * 8);
#pragma unroll
    for (int j = 0; j < 8; ++j) {
      XwT[(i * 8 + j) * 72 + lane] = f2s(w * s2f(xv[j]));
      BT[(i * 8 + j) * 72 + lane]  = bv[j];
    }
  }
  __syncthreads();

  const int r16 = lane & 15, q = lane >> 4;
  floatx4 acc[4][4] = {};
#pragma unroll
  for (int kk = 0; kk < 64; kk += 32) {
    short8 af[4], bfr[4];
#pragma unroll
    for (int i = 0; i < 4; ++i) af[i]  = *(const short8*)&XwT[(i * 16 + r16) * 72 + kk + q * 8];
#pragma unroll
    for (int j = 0; j < 4; ++j) bfr[j] = *(const short8*)&BT[(j * 16 + r16) * 72 + kk + q * 8];
#pragma unroll
    for (int i = 0; i < 4; ++i)
#pragma unroll
      for (int j = 0; j < 4; ++j)
        acc[i][j] = __builtin_amdgcn_mfma_f32_16x16x32_bf16(af[i], bfr[j], acc[i][j], 0, 0, 0);
  }
  float* Sout = Sbuf + (size_t)(bh * NCHUNK + c) * 4096;
#pragma unroll
  for (int i = 0; i < 4; ++i)
#pragma unroll
    for (int j = 0; j < 4; ++j)
#pragma unroll
      for (int r = 0; r < 4; ++r)
        Sout[(i * 16 + q * 4 + r) * 64 + (j * 16 + r16)] = acc[i][j][r];
}

// ---------------- SSD phase B: serial chunk combine (scalar decay) ----------------
__global__ __launch_bounds__(64)
void combine_kernel(const float* __restrict__ Sbuf, const float* __restrict__ Pbuf,
                    bf16* __restrict__ HinB)
{
  const int bh = blockIdx.x >> 2, slab = blockIdx.x & 3;
  const int base = slab * 1024 + threadIdx.x * 16;
  float h[16];
#pragma unroll
  for (int k = 0; k < 16; ++k) h[k] = 0.f;
  for (int c = 0; c < NCHUNK; ++c) {
    size_t off = (size_t)(bh * NCHUNK + c) * 4096 + base;
    union { short s[16]; uint4 q[2]; } pk;
#pragma unroll
    for (int k = 0; k < 16; ++k) pk.s[k] = f2s(h[k]);
    *(uint4*)(HinB + off)     = pk.q[0];
    *(uint4*)(HinB + off + 8) = pk.q[1];
    float P = Pbuf[bh * NCHUNK + c];
    const float4* S4 = (const float4*)(Sbuf + off);
#pragma unroll
    for (int k = 0; k < 4; ++k) {
      float4 s = S4[k];
      h[k*4+0] = h[k*4+0] * P + s.x;
      h[k*4+1] = h[k*4+1] * P + s.y;
      h[k*4+2] = h[k*4+2] * P + s.z;
      h[k*4+3] = h[k*4+3] * P + s.w;
    }
  }
}

// ---------------- SSD phase C: Y = (mask ⊙ C B^T) @ Xdt + (e^E C) @ Hin^T + D x ----------------
__global__ __launch_bounds__(64)
void y_kernel(const bf16* __restrict__ xbc, const bf16* __restrict__ Bb,
              const bf16* __restrict__ Cbb, const float* __restrict__ dtb,
              const bf16* __restrict__ HinB, const float* __restrict__ A_log,
              const float* __restrict__ Dp, bf16* __restrict__ yout)
{
  const int blk = blockIdx.x;
  const int c = blk & 31, h = (blk >> 5) & 31, b = blk >> 10;
  const int bh = b * 32 + h;
  const int lane = threadIdx.x;              // = s for the builds
  const int row0 = b * SEQLEN + c * 64;
  const int row = row0 + lane;
  const float Ah = -__expf(A_log[h]);
  const float Dh = Dp[h];

  __shared__ __align__(16) short XdT[64 * 72];  // [p][s]
  __shared__ __align__(16) short Msh[64 * 72];  // [t][s]
  __shared__ float Esh[64];

  float dts = dtb[row * NHEADS + h];
  float E = wave_incl_prefix(dts * Ah, lane);
  Esh[lane] = E;

  const bf16* xrow = xbc + (size_t)row * CONVDIM + h * 64;
#pragma unroll
  for (int i = 0; i < 8; ++i) {
    short8 xv = *(const short8*)(xrow + i * 8);
#pragma unroll
    for (int j = 0; j < 8; ++j)
      XdT[(i * 8 + j) * 72 + lane] = f2s(dts * s2f(xv[j]));
  }
  __syncthreads();

  const int r16 = lane & 15, q = lane >> 4;

  // G = C @ B^T  (t x s)
  floatx4 accg[4][4] = {};
#pragma unroll
  for (int kk = 0; kk < 64; kk += 32) {
    short8 af[4], bfr[4];
#pragma unroll
    for (int i = 0; i < 4; ++i)
      af[i]  = *(const short8*)(Cbb + (size_t)(row0 + i * 16 + r16) * DSTATE + kk + q * 8);
#pragma unroll
    for (int j = 0; j < 4; ++j)
      bfr[j] = *(const short8*)(Bb + (size_t)(row0 + j * 16 + r16) * DSTATE + kk + q * 8);
#pragma unroll
    for (int i = 0; i < 4; ++i)
#pragma unroll
      for (int j = 0; j < 4; ++j)
        accg[i][j] = __builtin_amdgcn_mfma_f32_16x16x32_bf16(af[i], bfr[j], accg[i][j], 0, 0, 0);
  }
  // causal decay mask -> Msh (bf16, A-operand layout for next MFMA)
#pragma unroll
  for (int i = 0; i < 4; ++i)
#pragma unroll
    for (int j = 0; j < 4; ++j)
#pragma unroll
      for (int r = 0; r < 4; ++r) {
        int t = i * 16 + q * 4 + r;
        int s = j * 16 + r16;
        float v = (s <= t) ? __expf(Esh[t] - Esh[s]) * accg[i][j][r] : 0.f;
        Msh[t * 72 + s] = f2s(v);
      }
  __syncthreads();

  floatx4 acc[4][4] = {};
  // Y_intra = M @ Xdt   (t x p)
#pragma unroll
  for (int kk = 0; kk < 64; kk += 32) {
    short8 af[4], bfr[4];
#pragma unroll
    for (int i = 0; i < 4; ++i) af[i]  = *(const short8*)&Msh[(i * 16 + r16) * 72 + kk + q * 8];
#pragma unroll
    for (int j = 0; j < 4; ++j) bfr[j] = *(const short8*)&XdT[(j * 16 + r16) * 72 + kk + q * 8];
#pragma unroll
    for (int i = 0; i < 4; ++i)
#pragma unroll
      for (int j = 0; j < 4; ++j)
        acc[i][j] = __builtin_amdgcn_mfma_f32_16x16x32_bf16(af[i], bfr[j], acc[i][j], 0, 0, 0);
  }
  // Y_inter = (e^{E_t} C) @ Hin^T   (t x p)
  float ei[4];
#pragma unroll
  for (int i = 0; i < 4; ++i) ei[i] = __expf(Esh[i * 16 + r16]);
  const bf16* hinp = HinB + (size_t)(bh * NCHUNK + c) * 4096;
#pragma unroll
  for (int kk = 0; kk < 64; kk += 32) {
    short8 af[4], bfr[4];
#pragma unroll
    for (int i = 0; i < 4; ++i) {
      short8 cv = *(const short8*)(Cbb + (size_t)(row0 + i * 16 + r16) * DSTATE + kk + q * 8);
#pragma unroll
      for (int jj = 0; jj < 8; ++jj) af[i][jj] = f2s(ei[i] * s2f(cv[jj]));
    }
#pragma unroll
    for (int j = 0; j < 4; ++j)
      bfr[j] = *(const short8*)(hinp + (j * 16 + r16) * 64 + kk + q * 8);
#pragma unroll
    for (int i = 0; i < 4; ++i)
#pragma unroll
      for (int j = 0; j < 4; ++j)
        acc[i][j] = __builtin_amdgcn_mfma_f32_16x16x32_bf16(af[i], bfr[j], acc[i][j], 0, 0, 0);
  }
  // epilogue: + D * x, store bf16
#pragma unroll
  for (int i = 0; i < 4; ++i)
#pragma unroll
    for (int j = 0; j < 4; ++j)
#pragma unroll
      for (int r = 0; r < 4; ++r) {
        int t = i * 16 + q * 4 + r;
        int p = j * 16 + r16;
        int g = row0 + t;
        float y = acc[i][j][r] + Dh * b2f(xbc[(size_t)g * CONVDIM + h * 64 + p]);
        yout[(size_t)g * DINNER + h * 64 + p] = f2b(y);
      }
}

// ---------------- gate (y * silu(z)) + RMSNorm ----------------
// G13: thread t owns cols 8t..8t+7 -> 2x short8 loads, short8 store.
__global__ void gate_rms_kernel(const bf16* __restrict__ y, const bf16* __restrict__ zx,
                                const float* __restrict__ nw, bf16* __restrict__ yn)
{
  int row = blockIdx.x, tid = threadIdx.x;
  int c0 = tid * 8;
  short8 zv = *(const short8*)(zx + (size_t)row * DINPROJ + c0);
  short8 yv = *(const short8*)(y  + (size_t)row * DINNER  + c0);
  float v[8]; float ss = 0.f, dummy = 0.f;
#pragma unroll
  for (int j = 0; j < 8; ++j) {
    float z = s2f(zv[j]);
    float g = z / (1.f + __expf(-z));
    float val = s2f(yv[j]) * g;
    v[j] = val; ss += val * val;
  }
  block_reduce_2(ss, dummy);
  float rs = rsqrtf(ss * (1.f / DINNER) + 1e-5f);
  float4 w0 = *(const float4*)(nw + c0);
  float4 w1 = *(const float4*)(nw + c0 + 4);
  short8 outv;
  outv[0] = f2s(v[0] * rs * w0.x); outv[1] = f2s(v[1] * rs * w0.y);
  outv[2] = f2s(v[2] * rs * w0.z); outv[3] = f2s(v[3] * rs * w0.w);
  outv[4] = f2s(v[4] * rs * w1.x); outv[5] = f2s(v[5] * rs * w1.y);
  outv[6] = f2s(v[6] * rs * w1.z); outv[7] = f2s(v[7] * rs * w1.w);
  *(short8*)(yn + (size_t)row * DINNER + c0) = outv;
}

extern "C" void kernel_launch(void* const* d_in, const int* in_sizes, int n_in,
                              void* d_out, int out_size, void* d_ws, size_t ws_size,
                              hipStream_t stream)
{
  const float* x         = (const float*)d_in[0];
  const float* ln1_w     = (const float*)d_in[1];
  const float* ln1_b     = (const float*)d_in[2];
  const float* in_proj_w = (const float*)d_in[3];
  const float* conv_w    = (const float*)d_in[4];
  const float* conv_b    = (const float*)d_in[5];
  const float* dt_bias   = (const float*)d_in[6];
  const float* A_log     = (const float*)d_in[7];
  const float* Dp        = (const float*)d_in[8];
  const float* norm_w    = (const float*)d_in[9];
  const float* out_proj_w= (const float*)d_in[10];
  const float* ln2_w     = (const float*)d_in[11];
  const float* ln2_b     = (const float*)d_in[12];
  const float* mlp_w1    = (const float*)d_in[13];
  const float* mlp_b1    = (const float*)d_in[14];
  const float* mlp_w2    = (const float*)d_in[15];
  const float* mlp_b2    = (const float*)d_in[16];

  char* ws = (char*)d_ws;
  bf16*  zx   = (bf16*)(ws + 0);            // 34,865,152
  bf16*  h1   = (bf16*)(ws + 34865152);     //  8,388,608
  bf16*  xbc  = (bf16*)(ws + 43253760);     // 17,825,792 (reused as w2b)
  bf16*  Bb   = (bf16*)(ws + 61079552);     //    524,288
  bf16*  Cbb  = (bf16*)(ws + 61603840);     //    524,288
  float* dtb  = (float*)(ws + 62128128);    //    524,288
  float* Pbuf = (float*)(ws + 62652416);    //      8,192
  float* Sbuf = (float*)(ws + 62660608);    // 33,554,432 fp32 (dead after combine)
  bf16*  yw   = (bf16*)(ws + 62660608);     // 16,777,216 bf16 (alias Sbuf lower; Sbuf dead)
  bf16*  x2   = (bf16*)(ws + 79437824);     //  8,388,608 bf16 (alias Sbuf upper; yw-disjoint)
  bf16*  HinB = (bf16*)(ws + 96215040);     //  8,388,608
  bf16*  yn   = (bf16*)(ws + 96215040);     // 16,777,216 (overlays HinB; HinB dead after y_kernel)
  bf16*  wip  = (bf16*)(ws + 112992256);    //  8,716,288 (reused as w1b)
  bf16*  wop  = (bf16*)(ws + 121708544);    //  4,194,304 -> end 125,902,848
  bf16*  h2n  = h1;
  bf16*  mid  = zx;
  bf16*  w1b  = wip;
  bf16*  w2b  = xbc;

  // 0a. convert in_proj_w to bf16
  cvt_kernel<<<(4256 * 1024 / 4 + 255) / 256, 256, 0, stream>>>(in_proj_w, wip, 4256 * 1024 / 4);
  // 1. LN1
  ln_kernel<float><<<ROWS, 256, 0, stream>>>(x, ln1_w, ln1_b, h1);
  // 2. in_proj   [256x128 tile; grid x = M-tiles (16), y = N-tiles (34, guarded)]
  gemm_bt_256128<0><<<dim3(16, 34), 512, 0, stream>>>(h1, wip, nullptr, nullptr, zx,
                                                      ROWS, DINPROJ, DMODEL);
  // 0b. convert mlp_w1 (into wip region) and out_proj_w
  cvt_kernel<<<(4096 * 1024 / 4 + 255) / 256, 256, 0, stream>>>(mlp_w1, w1b, 4096 * 1024 / 4);
  cvt_kernel<<<(1024 * 2048 / 4 + 255) / 256, 256, 0, stream>>>(out_proj_w, wop, 1024 * 2048 / 4);
  // 3. conv + SiLU + softplus(dt)
  conv_kernel<<<ROWS, 256, 0, stream>>>(zx, conv_w, conv_b, dt_bias, xbc, Bb, Cbb, dtb);
  // 4a. SSD phase A: per-chunk end states
  chunk_state_kernel<<<2048, 64, 0, stream>>>(xbc, Bb, dtb, A_log, Sbuf, Pbuf);
  // 4b. SSD phase B: combine chunk states
  combine_kernel<<<256, 64, 0, stream>>>(Sbuf, Pbuf, HinB);
  // 4c. SSD phase C: outputs (bf16)
  y_kernel<<<2048, 64, 0, stream>>>(xbc, Bb, Cbb, dtb, HinB, A_log, Dp, yw);
  // 0c. convert mlp_w2 (xbc region dead now)
  cvt_kernel<<<(1024 * 4096 / 4 + 255) / 256, 256, 0, stream>>>(mlp_w2, w2b, 1024 * 4096 / 4);
  // 5. gate + RMSNorm
  gate_rms_kernel<<<ROWS, 256, 0, stream>>>(yw, zx, norm_w, yn);
  // 6. out_proj + residual(x, fp32) -> x2 (bf16)   [64x64 2-phase, 1024 blocks]
  gemm_bt_6464<2><<<dim3(64, 16), 256, 0, stream>>>(yn, wop, nullptr, x, (void*)x2,
                                                    ROWS, DMODEL, DINNER);
  // 7. LN2 (bf16 in)
  ln_kernel<bf16><<<ROWS, 256, 0, stream>>>(x2, ln2_w, ln2_b, h2n);
  // 8. mlp1 + bias + GELU   [256x128 tile; grid (16, 32)]
  gemm_bt_256128<1><<<dim3(16, 32), 512, 0, stream>>>(h2n, w1b, mlp_b1, nullptr, mid,
                                                      ROWS, 4 * DMODEL, DMODEL);
  // 9. mlp2 + bias + residual(x2, bf16) -> out (fp32)   [64x64 2-phase, 1024 blocks]
  gemm_bt_6464<3><<<dim3(64, 16), 256, 0, stream>>>(mid, w2b, mlp_b2, x2, d_out,
                                                    ROWS, DMODEL, 4 * DMODEL);
}

// Round 8
// 428.961 us; speedup vs baseline: 1.9486x; 1.9486x over previous
//
#include <hip/hip_runtime.h>
#include <hip/hip_bf16.h>
#include <math.h>

using bf16 = __hip_bfloat16;
typedef __attribute__((ext_vector_type(8))) short short8;
typedef __attribute__((ext_vector_type(4))) short short4v;
typedef __attribute__((ext_vector_type(4))) float floatx4;

#define SEQLEN   2048
#define ROWS     4096      // B*L
#define DMODEL   1024
#define DINNER   2048
#define NHEADS   32
#define HEADDIM  64
#define DSTATE   64
#define CONVDIM  2176
#define DINPROJ  4256
#define NCHUNK   32        // 2048 / 64

__device__ __forceinline__ float b2f(bf16 x) { return __bfloat162float(x); }
__device__ __forceinline__ bf16  f2b(float x) { return __float2bfloat16(x); }
__device__ __forceinline__ float s2f(short s) { union { short s; bf16 b; } u; u.s = s; return b2f(u.b); }
__device__ __forceinline__ short f2s(float f) { union { short s; bf16 b; } u; u.b = f2b(f); return u.s; }

// vectorized 4-wide loads (fp32 / bf16) -> fp32
__device__ __forceinline__ void load4(const float* p, float* v) {
  float4 t = *(const float4*)p; v[0] = t.x; v[1] = t.y; v[2] = t.z; v[3] = t.w;
}
__device__ __forceinline__ void load4(const bf16* p, float* v) {
  short4v t = *(const short4v*)p;
#pragma unroll
  for (int j = 0; j < 4; ++j) v[j] = s2f(t[j]);
}

// ---------------- async global->LDS (16B per lane) ----------------
typedef __attribute__((address_space(1))) void v_as1;
typedef __attribute__((address_space(3))) void v_as3;
__device__ __forceinline__ void gload_lds16(const void* g, void* l) {
  __builtin_amdgcn_global_load_lds((v_as1*)(g), (v_as3*)(l), 16, 0, 0);
}

// ---------------- fp32 -> bf16 conversion (4 elems/thread) ----------------
__global__ void cvt_kernel(const float* __restrict__ in, bf16* __restrict__ out, int n4) {
  int i = blockIdx.x * 256 + threadIdx.x;
  if (i < n4) {
    float4 v = ((const float4*)in)[i];
    union { bf16 h[4]; uint2 u; } r;
    r.h[0] = f2b(v.x); r.h[1] = f2b(v.y); r.h[2] = f2b(v.z); r.h[3] = f2b(v.w);
    ((uint2*)out)[i] = r.u;
  }
}

// ---------------- block reduction (2 values, 256 threads) ----------------
__device__ __forceinline__ void block_reduce_2(float& a, float& b) {
#pragma unroll
  for (int off = 32; off > 0; off >>= 1) {
    a += __shfl_xor(a, off);
    b += __shfl_xor(b, off);
  }
  __shared__ float ra[4], rb[4];
  int w = threadIdx.x >> 6;
  if ((threadIdx.x & 63) == 0) { ra[w] = a; rb[w] = b; }
  __syncthreads();
  a = ra[0] + ra[1] + ra[2] + ra[3];
  b = rb[0] + rb[1] + rb[2] + rb[3];
}

// ---------------- LayerNorm (1024 cols, fp32/bf16 in, bf16 out) ----------------
// G13: one vector load per thread (thread t owns cols 4t..4t+3), vector store.
template<typename TIN>
__global__ void ln_kernel(const TIN* __restrict__ x, const float* __restrict__ w,
                          const float* __restrict__ b, bf16* __restrict__ out)
{
  int row = blockIdx.x;
  int c0  = threadIdx.x * 4;
  float v[4];
  load4(x + (size_t)row * DMODEL + c0, v);
  float s  = v[0] + v[1] + v[2] + v[3];
  float sq = v[0]*v[0] + v[1]*v[1] + v[2]*v[2] + v[3]*v[3];
  block_reduce_2(s, sq);
  float mu  = s * (1.f / DMODEL);
  float var = sq * (1.f / DMODEL) - mu * mu;
  float rs  = rsqrtf(var + 1e-5f);
  float4 wv = *(const float4*)(w + c0);
  float4 bv = *(const float4*)(b + c0);
  union { bf16 h[4]; uint2 u; } r;
  r.h[0] = f2b((v[0] - mu) * rs * wv.x + bv.x);
  r.h[1] = f2b((v[1] - mu) * rs * wv.y + bv.y);
  r.h[2] = f2b((v[2] - mu) * rs * wv.z + bv.z);
  r.h[3] = f2b((v[3] - mu) * rs * wv.w + bv.w);
  *(uint2*)(out + (size_t)row * DMODEL + c0) = r.u;
}

// ---------------- epilogue helper ----------------
// EPI 0: store bf16
// EPI 1: +bias(fp32), exact GELU, store bf16
// EPI 2: +resid(fp32), store bf16
// EPI 3: +bias(fp32) +resid(bf16), store fp32
template<int EPI>
__device__ __forceinline__ void epi_store(float v, size_t off, int col,
                                          const float* bias, const void* resid, void* Cout)
{
  if (EPI == 0) {
    ((bf16*)Cout)[off] = f2b(v);
  } else if (EPI == 1) {
    v += bias[col];
    v = 0.5f * v * (1.f + erff(v * 0.70710678118654752f));
    ((bf16*)Cout)[off] = f2b(v);
  } else if (EPI == 2) {
    v += ((const float*)resid)[off];
    ((bf16*)Cout)[off] = f2b(v);
  } else {
    v += bias[col] + b2f(((const bf16*)resid)[off]);
    ((float*)Cout)[off] = v;
  }
}

// XOR-swizzle: LDS slot (row, blk16) holds global block (blk16 ^ (row&7)).
// Staging keeps global_load_lds's contiguous lane->LDS mapping; readers XOR too.
//
// GEMM history (R0-R7, frozen lessons):
//  - R7 LESSON (launch_bounds spill): __launch_bounds__(512,6) demanded 6 waves/SIMD
//    -> VGPR cap ~85 < the ~110 this kernel needs -> compiler spilled acc[4][4] to
//    scratch (VGPR_Count=40, WRITE_SIZE=683MB, MfmaUtil 5%, 290us/dispatch). G1:
//    only request the occupancy the register budget allows. (512,4) -> cap 128,
//    no spill, 2 blocks/CU = 16 waves/CU (still 2x the old 128x128's wave count).
//  - sync-structure edits on the K=1024 GEMMs all lost (64KB dbuf -> occupancy
//    crash; BK=32 dbuf -> bank conflicts + 2x barrier rate).
//  - 64x64 2-phase counted-vmcnt stays for the N=1024 GEMMs (only consistent winner).

// ---------------- GEMM 256x128 tile, 512 thr, single-buffer BK=64 ----------------
template<int EPI>
__global__ __launch_bounds__(512, 4)
void gemm_bt_256128(const bf16* __restrict__ A, const bf16* __restrict__ W,
                    const float* __restrict__ bias, const void* __restrict__ resid,
                    void* __restrict__ Cout, int M, int N, int K)
{
  __shared__ __align__(16) short Asl[256 * 64];   // 32 KB
  __shared__ __align__(16) short Bsl[128 * 64];   // 16 KB -> 48 KB total
  const int tid  = threadIdx.x;
  const int lane = tid & 63;
  const int wv   = tid >> 6;          // 0..7
  const int wm   = wv >> 1;           // 0..3 : wave owns A rows wm*64..+63
  const int wn   = wv & 1;            // 0..1 : wave owns B rows wn*64..+63
  const int r16  = lane & 15, q = lane >> 4;
  const int m0   = blockIdx.x * 256;  // x = M-tile: XCD affinity on A rows
  const int n0   = blockIdx.y * 128;

  floatx4 acc[4][4] = {};

  for (int k0 = 0; k0 < K; k0 += 64) {
#pragma unroll
    for (int it = 0; it < 4; ++it) {
      int idx = it * 512 + tid;                   // 0..2047
      int row = idx >> 3;                         // 0..255
      int cb  = (((idx & 7) ^ (row & 7)) << 3);   // swizzled source block
      gload_lds16(A + (size_t)(m0 + row) * K + k0 + cb, &Asl[idx * 8]);
    }
#pragma unroll
    for (int it = 0; it < 2; ++it) {
      int idx = it * 512 + tid;                   // 0..1023
      int row = idx >> 3;                         // 0..127
      int grow = n0 + row; if (grow > N - 1) grow = N - 1;   // N-guard (in_proj N=4256)
      int cb  = (((idx & 7) ^ (row & 7)) << 3);
      gload_lds16(W + (size_t)grow * K + k0 + cb, &Bsl[idx * 8]);
    }
    __syncthreads();
#pragma unroll
    for (int kk = 0; kk < 64; kk += 32) {
      short8 af[4], bfr[4];
      const int lb = (kk >> 3) + q;               // logical 16B block 0..7
#pragma unroll
      for (int i = 0; i < 4; ++i) {
        int ar = wm * 64 + i * 16 + r16;
        af[i] = *(const short8*)&Asl[ar * 64 + ((lb ^ (ar & 7)) << 3)];
      }
#pragma unroll
      for (int j = 0; j < 4; ++j) {
        int br = wn * 64 + j * 16 + r16;
        bfr[j] = *(const short8*)&Bsl[br * 64 + ((lb ^ (br & 7)) << 3)];
      }
#pragma unroll
      for (int i = 0; i < 4; ++i)
#pragma unroll
        for (int j = 0; j < 4; ++j)
          acc[i][j] = __builtin_amdgcn_mfma_f32_16x16x32_bf16(af[i], bfr[j], acc[i][j], 0, 0, 0);
    }
    __syncthreads();
  }

#pragma unroll
  for (int i = 0; i < 4; ++i)
#pragma unroll
    for (int j = 0; j < 4; ++j)
#pragma unroll
      for (int r = 0; r < 4; ++r) {
        int row = m0 + wm * 64 + i * 16 + q * 4 + r;
        int col = n0 + wn * 64 + j * 16 + r16;
        if (col < N)
          epi_store<EPI>(acc[i][j][r], (size_t)row * N + col, col, bias, resid, Cout);
      }
}

// ---------------- GEMM 64x64 tile (N=1024 GEMMs): 1024 blocks = 4/CU, 32 KB LDS ----------------
// 2-phase pipeline: stage tile t+1 into buf^1 BEFORE computing tile t; counted
// vmcnt(4) drains only tile t's loads while t+1's stay in flight across the barrier.
template<int EPI>
__global__ __launch_bounds__(256, 4)
void gemm_bt_6464(const bf16* __restrict__ A, const bf16* __restrict__ W,
                  const float* __restrict__ bias, const void* __restrict__ resid,
                  void* __restrict__ Cout, int M, int N, int K)
{
  __shared__ __align__(16) short Asl[2][64 * 64];    // 2 x 8 KB
  __shared__ __align__(16) short Bsl[2][64 * 64];    // 2 x 8 KB
  const int tid  = threadIdx.x;
  const int lane = tid & 63;
  const int wv   = tid >> 6;
  const int wm   = wv >> 1, wn = wv & 1;          // 2x2 wave grid of 32x32 sub-tiles
  const int r16  = lane & 15, q = lane >> 4;
  const int m0   = blockIdx.x * 64;               // x = M-tile: XCD pin on A rows
  const int n0   = blockIdx.y * 64;

  floatx4 acc[2][2] = {};

  auto stage = [&](int b, int k0) {
#pragma unroll
    for (int it = 0; it < 2; ++it) {
      int idx = it * 256 + tid;
      int cb  = (((idx & 7) ^ ((idx >> 3) & 7)) << 3);
      gload_lds16(A + (size_t)(m0 + (idx >> 3)) * K + k0 + cb, &Asl[b][idx * 8]);
    }
#pragma unroll
    for (int it = 0; it < 2; ++it) {
      int idx = it * 256 + tid;
      int cb  = (((idx & 7) ^ ((idx >> 3) & 7)) << 3);
      gload_lds16(W + (size_t)(n0 + (idx >> 3)) * K + k0 + cb, &Bsl[b][idx * 8]);
    }
  };
  auto compute = [&](int b) {
#pragma unroll
    for (int kk = 0; kk < 64; kk += 32) {
      short8 af[2], bfr[2];
      const int lb = (kk >> 3) + q;
#pragma unroll
      for (int i = 0; i < 2; ++i) {
        int ar = wm * 32 + i * 16 + r16;
        af[i] = *(const short8*)&Asl[b][ar * 64 + ((lb ^ (ar & 7)) << 3)];
      }
#pragma unroll
      for (int j = 0; j < 2; ++j) {
        int br = wn * 32 + j * 16 + r16;
        bfr[j] = *(const short8*)&Bsl[b][br * 64 + ((lb ^ (br & 7)) << 3)];
      }
#pragma unroll
      for (int i = 0; i < 2; ++i)
#pragma unroll
        for (int j = 0; j < 2; ++j)
          acc[i][j] = __builtin_amdgcn_mfma_f32_16x16x32_bf16(af[i], bfr[j], acc[i][j], 0, 0, 0);
    }
  };

  stage(0, 0);
  const int nt = K >> 6;
  int cur = 0;
  for (int t = 0; t < nt - 1; ++t) {
    stage(cur ^ 1, (t + 1) << 6);                 // 4 loads/thread in flight
    asm volatile("s_waitcnt vmcnt(4)" ::: "memory");   // drain tile t only
    __builtin_amdgcn_s_barrier();
    compute(cur);
    asm volatile("s_waitcnt lgkmcnt(0)" ::: "memory");
    __builtin_amdgcn_s_barrier();
    cur ^= 1;
  }
  asm volatile("s_waitcnt vmcnt(0)" ::: "memory");
  __builtin_amdgcn_s_barrier();
  compute(cur);

#pragma unroll
  for (int i = 0; i < 2; ++i)
#pragma unroll
    for (int j = 0; j < 2; ++j)
#pragma unroll
      for (int r = 0; r < 4; ++r) {
        int row = m0 + wm * 32 + i * 16 + q * 4 + r;
        int col = n0 + wn * 32 + j * 16 + r16;
        epi_store<EPI>(acc[i][j][r], (size_t)row * N + col, col, bias, resid, Cout);
      }
}

// ---------------- depthwise causal conv (4 tap) + SiLU + softplus(dt) ----------------
// G13: 8-contiguous-channel groups per thread -> 4x short8 tap loads + 8x float4
// weight loads + short8 stores.
__global__ void conv_kernel(const bf16* __restrict__ zx, const float* __restrict__ cw,
                            const float* __restrict__ cb, const float* __restrict__ dtbias,
                            bf16* __restrict__ xbc, bf16* __restrict__ Bb,
                            bf16* __restrict__ Cbb, float* __restrict__ dtb)
{
  int row = blockIdx.x;
  int b = row >> 11, t = row & 2047;
  const size_t rowbase = (size_t)(b * SEQLEN) * DINPROJ + DINNER;
  for (int c8 = threadIdx.x; c8 < CONVDIM / 8; c8 += 256) {
    int c = c8 * 8;
    float acc[8];
    {
      float4 b0 = *(const float4*)(cb + c);
      float4 b1 = *(const float4*)(cb + c + 4);
      acc[0] = b0.x; acc[1] = b0.y; acc[2] = b0.z; acc[3] = b0.w;
      acc[4] = b1.x; acc[5] = b1.y; acc[6] = b1.z; acc[7] = b1.w;
    }
    float4 wj[8];
#pragma unroll
    for (int j = 0; j < 8; ++j) wj[j] = *(const float4*)(cw + (c + j) * 4);
    short8 xv[4];
#pragma unroll
    for (int k = 0; k < 4; ++k) {
      int tt = t + k - 3;
      if (tt >= 0) {
        xv[k] = *(const short8*)(zx + rowbase + (size_t)tt * DINPROJ + c);
#pragma unroll
        for (int j = 0; j < 8; ++j) {
          float wk = (k == 0) ? wj[j].x : (k == 1) ? wj[j].y : (k == 2) ? wj[j].z : wj[j].w;
          acc[j] += s2f(xv[k][j]) * wk;
        }
      }
    }
    short8 outv;
#pragma unroll
    for (int j = 0; j < 8; ++j) {
      float s = acc[j] / (1.f + __expf(-acc[j]));   // SiLU
      outv[j] = f2s(s);
    }
    *(short8*)(xbc + (size_t)row * CONVDIM + c) = outv;
    if (c >= DINNER) {
      if (c < DINNER + DSTATE) *(short8*)(Bb + row * DSTATE + (c - DINNER)) = outv;
      else                     *(short8*)(Cbb + row * DSTATE + (c - DINNER - DSTATE)) = outv;
    }
  }
  if (threadIdx.x < NHEADS) {
    int hh = threadIdx.x;
    float raw = b2f(zx[(size_t)row * DINPROJ + DINNER + CONVDIM + hh]) + dtbias[hh];
    float dt = raw > 20.f ? raw : log1pf(__expf(raw));   // softplus
    dtb[row * NHEADS + hh] = dt;
  }
}

// ---------------- wave inclusive prefix sum helper ----------------
__device__ __forceinline__ float wave_incl_prefix(float a, int lane) {
#pragma unroll
  for (int off = 1; off < 64; off <<= 1) {
    float o = __shfl_up(a, off);
    if (lane >= off) a += o;
  }
  return a;
}

// ---------------- SSD phase A: chunk end-state S = Xw^T @ B, decay P ----------------
__global__ __launch_bounds__(64)
void chunk_state_kernel(const bf16* __restrict__ xbc, const bf16* __restrict__ Bb,
                        const float* __restrict__ dtb, const float* __restrict__ A_log,
                        float* __restrict__ Sbuf, float* __restrict__ Pbuf)
{
  const int blk = blockIdx.x;
  const int c = blk & 31, h = (blk >> 5) & 31, b = blk >> 10;
  const int bh = b * 32 + h;
  const int lane = threadIdx.x;              // = s (timestep within chunk)
  const int row = b * SEQLEN + c * 64 + lane;
  const float Ah = -__expf(A_log[h]);

  float dts = dtb[row * NHEADS + h];
  float E = wave_incl_prefix(dts * Ah, lane);
  float EQ = __shfl(E, 63);
  float w = __expf(EQ - E) * dts;
  if (lane == 63) Pbuf[bh * NCHUNK + c] = __expf(EQ);

  __shared__ __align__(16) short XwT[64 * 72];   // [p][s] pad 72
  __shared__ __align__(16) short BT[64 * 72];    // [n][s] pad 72

  const bf16* xrow = xbc + (size_t)row * CONVDIM + h * 64;
  const bf16* brow = Bb + (size_t)row * DSTATE;
#pragma unroll
  for (int i = 0; i < 8; ++i) {
    short8 xv = *(const short8*)(xrow + i * 8);
    short8 bv = *(const short8*)(brow + i * 8);
#pragma unroll
    for (int j = 0; j < 8; ++j) {
      XwT[(i * 8 + j) * 72 + lane] = f2s(w * s2f(xv[j]));
      BT[(i * 8 + j) * 72 + lane]  = bv[j];
    }
  }
  __syncthreads();

  const int r16 = lane & 15, q = lane >> 4;
  floatx4 acc[4][4] = {};
#pragma unroll
  for (int kk = 0; kk < 64; kk += 32) {
    short8 af[4], bfr[4];
#pragma unroll
    for (int i = 0; i < 4; ++i) af[i]  = *(const short8*)&XwT[(i * 16 + r16) * 72 + kk + q * 8];
#pragma unroll
    for (int j = 0; j < 4; ++j) bfr[j] = *(const short8*)&BT[(j * 16 + r16) * 72 + kk + q * 8];
#pragma unroll
    for (int i = 0; i < 4; ++i)
#pragma unroll
      for (int j = 0; j < 4; ++j)
        acc[i][j] = __builtin_amdgcn_mfma_f32_16x16x32_bf16(af[i], bfr[j], acc[i][j], 0, 0, 0);
  }
  float* Sout = Sbuf + (size_t)(bh * NCHUNK + c) * 4096;
#pragma unroll
  for (int i = 0; i < 4; ++i)
#pragma unroll
    for (int j = 0; j < 4; ++j)
#pragma unroll
      for (int r = 0; r < 4; ++r)
        Sout[(i * 16 + q * 4 + r) * 64 + (j * 16 + r16)] = acc[i][j][r];
}

// ---------------- SSD phase B: serial chunk combine (scalar decay) ----------------
__global__ __launch_bounds__(64)
void combine_kernel(const float* __restrict__ Sbuf, const float* __restrict__ Pbuf,
                    bf16* __restrict__ HinB)
{
  const int bh = blockIdx.x >> 2, slab = blockIdx.x & 3;
  const int base = slab * 1024 + threadIdx.x * 16;
  float h[16];
#pragma unroll
  for (int k = 0; k < 16; ++k) h[k] = 0.f;
  for (int c = 0; c < NCHUNK; ++c) {
    size_t off = (size_t)(bh * NCHUNK + c) * 4096 + base;
    union { short s[16]; uint4 q[2]; } pk;
#pragma unroll
    for (int k = 0; k < 16; ++k) pk.s[k] = f2s(h[k]);
    *(uint4*)(HinB + off)     = pk.q[0];
    *(uint4*)(HinB + off + 8) = pk.q[1];
    float P = Pbuf[bh * NCHUNK + c];
    const float4* S4 = (const float4*)(Sbuf + off);
#pragma unroll
    for (int k = 0; k < 4; ++k) {
      float4 s = S4[k];
      h[k*4+0] = h[k*4+0] * P + s.x;
      h[k*4+1] = h[k*4+1] * P + s.y;
      h[k*4+2] = h[k*4+2] * P + s.z;
      h[k*4+3] = h[k*4+3] * P + s.w;
    }
  }
}

// ---------------- SSD phase C: Y = (mask ⊙ C B^T) @ Xdt + (e^E C) @ Hin^T + D x ----------------
__global__ __launch_bounds__(64)
void y_kernel(const bf16* __restrict__ xbc, const bf16* __restrict__ Bb,
              const bf16* __restrict__ Cbb, const float* __restrict__ dtb,
              const bf16* __restrict__ HinB, const float* __restrict__ A_log,
              const float* __restrict__ Dp, bf16* __restrict__ yout)
{
  const int blk = blockIdx.x;
  const int c = blk & 31, h = (blk >> 5) & 31, b = blk >> 10;
  const int bh = b * 32 + h;
  const int lane = threadIdx.x;              // = s for the builds
  const int row0 = b * SEQLEN + c * 64;
  const int row = row0 + lane;
  const float Ah = -__expf(A_log[h]);
  const float Dh = Dp[h];

  __shared__ __align__(16) short XdT[64 * 72];  // [p][s]
  __shared__ __align__(16) short Msh[64 * 72];  // [t][s]
  __shared__ float Esh[64];

  float dts = dtb[row * NHEADS + h];
  float E = wave_incl_prefix(dts * Ah, lane);
  Esh[lane] = E;

  const bf16* xrow = xbc + (size_t)row * CONVDIM + h * 64;
#pragma unroll
  for (int i = 0; i < 8; ++i) {
    short8 xv = *(const short8*)(xrow + i * 8);
#pragma unroll
    for (int j = 0; j < 8; ++j)
      XdT[(i * 8 + j) * 72 + lane] = f2s(dts * s2f(xv[j]));
  }
  __syncthreads();

  const int r16 = lane & 15, q = lane >> 4;

  // G = C @ B^T  (t x s)
  floatx4 accg[4][4] = {};
#pragma unroll
  for (int kk = 0; kk < 64; kk += 32) {
    short8 af[4], bfr[4];
#pragma unroll
    for (int i = 0; i < 4; ++i)
      af[i]  = *(const short8*)(Cbb + (size_t)(row0 + i * 16 + r16) * DSTATE + kk + q * 8);
#pragma unroll
    for (int j = 0; j < 4; ++j)
      bfr[j] = *(const short8*)(Bb + (size_t)(row0 + j * 16 + r16) * DSTATE + kk + q * 8);
#pragma unroll
    for (int i = 0; i < 4; ++i)
#pragma unroll
      for (int j = 0; j < 4; ++j)
        accg[i][j] = __builtin_amdgcn_mfma_f32_16x16x32_bf16(af[i], bfr[j], accg[i][j], 0, 0, 0);
  }
  // causal decay mask -> Msh (bf16, A-operand layout for next MFMA)
#pragma unroll
  for (int i = 0; i < 4; ++i)
#pragma unroll
    for (int j = 0; j < 4; ++j)
#pragma unroll
      for (int r = 0; r < 4; ++r) {
        int t = i * 16 + q * 4 + r;
        int s = j * 16 + r16;
        float v = (s <= t) ? __expf(Esh[t] - Esh[s]) * accg[i][j][r] : 0.f;
        Msh[t * 72 + s] = f2s(v);
      }
  __syncthreads();

  floatx4 acc[4][4] = {};
  // Y_intra = M @ Xdt   (t x p)
#pragma unroll
  for (int kk = 0; kk < 64; kk += 32) {
    short8 af[4], bfr[4];
#pragma unroll
    for (int i = 0; i < 4; ++i) af[i]  = *(const short8*)&Msh[(i * 16 + r16) * 72 + kk + q * 8];
#pragma unroll
    for (int j = 0; j < 4; ++j) bfr[j] = *(const short8*)&XdT[(j * 16 + r16) * 72 + kk + q * 8];
#pragma unroll
    for (int i = 0; i < 4; ++i)
#pragma unroll
      for (int j = 0; j < 4; ++j)
        acc[i][j] = __builtin_amdgcn_mfma_f32_16x16x32_bf16(af[i], bfr[j], acc[i][j], 0, 0, 0);
  }
  // Y_inter = (e^{E_t} C) @ Hin^T   (t x p)
  float ei[4];
#pragma unroll
  for (int i = 0; i < 4; ++i) ei[i] = __expf(Esh[i * 16 + r16]);
  const bf16* hinp = HinB + (size_t)(bh * NCHUNK + c) * 4096;
#pragma unroll
  for (int kk = 0; kk < 64; kk += 32) {
    short8 af[4], bfr[4];
#pragma unroll
    for (int i = 0; i < 4; ++i) {
      short8 cv = *(const short8*)(Cbb + (size_t)(row0 + i * 16 + r16) * DSTATE + kk + q * 8);
#pragma unroll
      for (int jj = 0; jj < 8; ++jj) af[i][jj] = f2s(ei[i] * s2f(cv[jj]));
    }
#pragma unroll
    for (int j = 0; j < 4; ++j)
      bfr[j] = *(const short8*)(hinp + (j * 16 + r16) * 64 + kk + q * 8);
#pragma unroll
    for (int i = 0; i < 4; ++i)
#pragma unroll
      for (int j = 0; j < 4; ++j)
        acc[i][j] = __builtin_amdgcn_mfma_f32_16x16x32_bf16(af[i], bfr[j], acc[i][j], 0, 0, 0);
  }
  // epilogue: + D * x, store bf16
#pragma unroll
  for (int i = 0; i < 4; ++i)
#pragma unroll
    for (int j = 0; j < 4; ++j)
#pragma unroll
      for (int r = 0; r < 4; ++r) {
        int t = i * 16 + q * 4 + r;
        int p = j * 16 + r16;
        int g = row0 + t;
        float y = acc[i][j][r] + Dh * b2f(xbc[(size_t)g * CONVDIM + h * 64 + p]);
        yout[(size_t)g * DINNER + h * 64 + p] = f2b(y);
      }
}

// ---------------- gate (y * silu(z)) + RMSNorm ----------------
// G13: thread t owns cols 8t..8t+7 -> 2x short8 loads, short8 store.
__global__ void gate_rms_kernel(const bf16* __restrict__ y, const bf16* __restrict__ zx,
                                const float* __restrict__ nw, bf16* __restrict__ yn)
{
  int row = blockIdx.x, tid = threadIdx.x;
  int c0 = tid * 8;
  short8 zv = *(const short8*)(zx + (size_t)row * DINPROJ + c0);
  short8 yv = *(const short8*)(y  + (size_t)row * DINNER  + c0);
  float v[8]; float ss = 0.f, dummy = 0.f;
#pragma unroll
  for (int j = 0; j < 8; ++j) {
    float z = s2f(zv[j]);
    float g = z / (1.f + __expf(-z));
    float val = s2f(yv[j]) * g;
    v[j] = val; ss += val * val;
  }
  block_reduce_2(ss, dummy);
  float rs = rsqrtf(ss * (1.f / DINNER) + 1e-5f);
  float4 w0 = *(const float4*)(nw + c0);
  float4 w1 = *(const float4*)(nw + c0 + 4);
  short8 outv;
  outv[0] = f2s(v[0] * rs * w0.x); outv[1] = f2s(v[1] * rs * w0.y);
  outv[2] = f2s(v[2] * rs * w0.z); outv[3] = f2s(v[3] * rs * w0.w);
  outv[4] = f2s(v[4] * rs * w1.x); outv[5] = f2s(v[5] * rs * w1.y);
  outv[6] = f2s(v[6] * rs * w1.z); outv[7] = f2s(v[7] * rs * w1.w);
  *(short8*)(yn + (size_t)row * DINNER + c0) = outv;
}

extern "C" void kernel_launch(void* const* d_in, const int* in_sizes, int n_in,
                              void* d_out, int out_size, void* d_ws, size_t ws_size,
                              hipStream_t stream)
{
  const float* x         = (const float*)d_in[0];
  const float* ln1_w     = (const float*)d_in[1];
  const float* ln1_b     = (const float*)d_in[2];
  const float* in_proj_w = (const float*)d_in[3];
  const float* conv_w    = (const float*)d_in[4];
  const float* conv_b    = (const float*)d_in[5];
  const float* dt_bias   = (const float*)d_in[6];
  const float* A_log     = (const float*)d_in[7];
  const float* Dp        = (const float*)d_in[8];
  const float* norm_w    = (const float*)d_in[9];
  const float* out_proj_w= (const float*)d_in[10];
  const float* ln2_w     = (const float*)d_in[11];
  const float* ln2_b     = (const float*)d_in[12];
  const float* mlp_w1    = (const float*)d_in[13];
  const float* mlp_b1    = (const float*)d_in[14];
  const float* mlp_w2    = (const float*)d_in[15];
  const float* mlp_b2    = (const float*)d_in[16];

  char* ws = (char*)d_ws;
  bf16*  zx   = (bf16*)(ws + 0);            // 34,865,152
  bf16*  h1   = (bf16*)(ws + 34865152);     //  8,388,608
  bf16*  xbc  = (bf16*)(ws + 43253760);     // 17,825,792 (reused as w2b)
  bf16*  Bb   = (bf16*)(ws + 61079552);     //    524,288
  bf16*  Cbb  = (bf16*)(ws + 61603840);     //    524,288
  float* dtb  = (float*)(ws + 62128128);    //    524,288
  float* Pbuf = (float*)(ws + 62652416);    //      8,192
  float* Sbuf = (float*)(ws + 62660608);    // 33,554,432 fp32 (dead after combine)
  bf16*  yw   = (bf16*)(ws + 62660608);     // 16,777,216 bf16 (alias Sbuf lower; Sbuf dead)
  bf16*  x2   = (bf16*)(ws + 79437824);     //  8,388,608 bf16 (alias Sbuf upper; yw-disjoint)
  bf16*  HinB = (bf16*)(ws + 96215040);     //  8,388,608
  bf16*  yn   = (bf16*)(ws + 96215040);     // 16,777,216 (overlays HinB; HinB dead after y_kernel)
  bf16*  wip  = (bf16*)(ws + 112992256);    //  8,716,288 (reused as w1b)
  bf16*  wop  = (bf16*)(ws + 121708544);    //  4,194,304 -> end 125,902,848
  bf16*  h2n  = h1;
  bf16*  mid  = zx;
  bf16*  w1b  = wip;
  bf16*  w2b  = xbc;

  // 0a. convert in_proj_w to bf16
  cvt_kernel<<<(4256 * 1024 / 4 + 255) / 256, 256, 0, stream>>>(in_proj_w, wip, 4256 * 1024 / 4);
  // 1. LN1
  ln_kernel<float><<<ROWS, 256, 0, stream>>>(x, ln1_w, ln1_b, h1);
  // 2. in_proj   [256x128 tile; grid x = M-tiles (16), y = N-tiles (34, guarded)]
  gemm_bt_256128<0><<<dim3(16, 34), 512, 0, stream>>>(h1, wip, nullptr, nullptr, zx,
                                                      ROWS, DINPROJ, DMODEL);
  // 0b. convert mlp_w1 (into wip region) and out_proj_w
  cvt_kernel<<<(4096 * 1024 / 4 + 255) / 256, 256, 0, stream>>>(mlp_w1, w1b, 4096 * 1024 / 4);
  cvt_kernel<<<(1024 * 2048 / 4 + 255) / 256, 256, 0, stream>>>(out_proj_w, wop, 1024 * 2048 / 4);
  // 3. conv + SiLU + softplus(dt)
  conv_kernel<<<ROWS, 256, 0, stream>>>(zx, conv_w, conv_b, dt_bias, xbc, Bb, Cbb, dtb);
  // 4a. SSD phase A: per-chunk end states
  chunk_state_kernel<<<2048, 64, 0, stream>>>(xbc, Bb, dtb, A_log, Sbuf, Pbuf);
  // 4b. SSD phase B: combine chunk states
  combine_kernel<<<256, 64, 0, stream>>>(Sbuf, Pbuf, HinB);
  // 4c. SSD phase C: outputs (bf16)
  y_kernel<<<2048, 64, 0, stream>>>(xbc, Bb, Cbb, dtb, HinB, A_log, Dp, yw);
  // 0c. convert mlp_w2 (xbc region dead now)
  cvt_kernel<<<(1024 * 4096 / 4 + 255) / 256, 256, 0, stream>>>(mlp_w2, w2b, 1024 * 4096 / 4);
  // 5. gate + RMSNorm
  gate_rms_kernel<<<ROWS, 256, 0, stream>>>(yw, zx, norm_w, yn);
  // 6. out_proj + residual(x, fp32) -> x2 (bf16)   [64x64 2-phase, 1024 blocks]
  gemm_bt_6464<2><<<dim3(64, 16), 256, 0, stream>>>(yn, wop, nullptr, x, (void*)x2,
                                                    ROWS, DMODEL, DINNER);
  // 7. LN2 (bf16 in)
  ln_kernel<bf16><<<ROWS, 256, 0, stream>>>(x2, ln2_w, ln2_b, h2n);
  // 8. mlp1 + bias + GELU   [256x128 tile; grid (16, 32)]
  gemm_bt_256128<1><<<dim3(16, 32), 512, 0, stream>>>(h2n, w1b, mlp_b1, nullptr, mid,
                                                      ROWS, 4 * DMODEL, DMODEL);
  // 9. mlp2 + bias + residual(x2, bf16) -> out (fp32)   [64x64 2-phase, 1024 blocks]
  gemm_bt_6464<3><<<dim3(64, 16), 256, 0, stream>>>(mid, w2b, mlp_b2, x2, d_out,
                                                    ROWS, DMODEL, 4 * DMODEL);
}

// Round 9
// 416.294 us; speedup vs baseline: 2.0079x; 1.0304x over previous
//
#include <hip/hip_runtime.h>
#include <hip/hip_bf16.h>
#include <math.h>

using bf16 = __hip_bfloat16;
typedef __attribute__((ext_vector_type(8))) short short8;
typedef __attribute__((ext_vector_type(4))) short short4v;
typedef __attribute__((ext_vector_type(4))) float floatx4;

#define SEQLEN   2048
#define ROWS     4096      // B*L
#define DMODEL   1024
#define DINNER   2048
#define NHEADS   32
#define HEADDIM  64
#define DSTATE   64
#define CONVDIM  2176
#define DINPROJ  4256
#define NCHUNK   32        // 2048 / 64

__device__ __forceinline__ float b2f(bf16 x) { return __bfloat162float(x); }
__device__ __forceinline__ bf16  f2b(float x) { return __float2bfloat16(x); }
__device__ __forceinline__ float s2f(short s) { union { short s; bf16 b; } u; u.s = s; return b2f(u.b); }
__device__ __forceinline__ short f2s(float f) { union { short s; bf16 b; } u; u.b = f2b(f); return u.s; }

// vectorized 4-wide loads (fp32 / bf16) -> fp32
__device__ __forceinline__ void load4(const float* p, float* v) {
  float4 t = *(const float4*)p; v[0] = t.x; v[1] = t.y; v[2] = t.z; v[3] = t.w;
}
__device__ __forceinline__ void load4(const bf16* p, float* v) {
  short4v t = *(const short4v*)p;
#pragma unroll
  for (int j = 0; j < 4; ++j) v[j] = s2f(t[j]);
}

// ---------------- async global->LDS (16B per lane) ----------------
typedef __attribute__((address_space(1))) void v_as1;
typedef __attribute__((address_space(3))) void v_as3;
__device__ __forceinline__ void gload_lds16(const void* g, void* l) {
  __builtin_amdgcn_global_load_lds((v_as1*)(g), (v_as3*)(l), 16, 0, 0);
}

// ---------------- fp32 -> bf16 conversion (4 elems/thread) ----------------
__global__ void cvt_kernel(const float* __restrict__ in, bf16* __restrict__ out, int n4) {
  int i = blockIdx.x * 256 + threadIdx.x;
  if (i < n4) {
    float4 v = ((const float4*)in)[i];
    union { bf16 h[4]; uint2 u; } r;
    r.h[0] = f2b(v.x); r.h[1] = f2b(v.y); r.h[2] = f2b(v.z); r.h[3] = f2b(v.w);
    ((uint2*)out)[i] = r.u;
  }
}

// ---------------- block reduction (2 values, 256 threads) ----------------
__device__ __forceinline__ void block_reduce_2(float& a, float& b) {
#pragma unroll
  for (int off = 32; off > 0; off >>= 1) {
    a += __shfl_xor(a, off);
    b += __shfl_xor(b, off);
  }
  __shared__ float ra[4], rb[4];
  int w = threadIdx.x >> 6;
  if ((threadIdx.x & 63) == 0) { ra[w] = a; rb[w] = b; }
  __syncthreads();
  a = ra[0] + ra[1] + ra[2] + ra[3];
  b = rb[0] + rb[1] + rb[2] + rb[3];
}

// ---------------- LayerNorm (1024 cols, fp32/bf16 in, bf16 out) ----------------
// G13: one vector load per thread (thread t owns cols 4t..4t+3), vector store.
template<typename TIN>
__global__ void ln_kernel(const TIN* __restrict__ x, const float* __restrict__ w,
                          const float* __restrict__ b, bf16* __restrict__ out)
{
  int row = blockIdx.x;
  int c0  = threadIdx.x * 4;
  float v[4];
  load4(x + (size_t)row * DMODEL + c0, v);
  float s  = v[0] + v[1] + v[2] + v[3];
  float sq = v[0]*v[0] + v[1]*v[1] + v[2]*v[2] + v[3]*v[3];
  block_reduce_2(s, sq);
  float mu  = s * (1.f / DMODEL);
  float var = sq * (1.f / DMODEL) - mu * mu;
  float rs  = rsqrtf(var + 1e-5f);
  float4 wv = *(const float4*)(w + c0);
  float4 bv = *(const float4*)(b + c0);
  union { bf16 h[4]; uint2 u; } r;
  r.h[0] = f2b((v[0] - mu) * rs * wv.x + bv.x);
  r.h[1] = f2b((v[1] - mu) * rs * wv.y + bv.y);
  r.h[2] = f2b((v[2] - mu) * rs * wv.z + bv.z);
  r.h[3] = f2b((v[3] - mu) * rs * wv.w + bv.w);
  *(uint2*)(out + (size_t)row * DMODEL + c0) = r.u;
}

// ---------------- epilogue helper ----------------
// EPI 0: store bf16
// EPI 1: +bias(fp32), exact GELU, store bf16
// EPI 2: +resid(fp32), store bf16
// EPI 3: +bias(fp32) +resid(bf16), store fp32
template<int EPI>
__device__ __forceinline__ void epi_store(float v, size_t off, int col,
                                          const float* bias, const void* resid, void* Cout)
{
  if (EPI == 0) {
    ((bf16*)Cout)[off] = f2b(v);
  } else if (EPI == 1) {
    v += bias[col];
    v = 0.5f * v * (1.f + erff(v * 0.70710678118654752f));
    ((bf16*)Cout)[off] = f2b(v);
  } else if (EPI == 2) {
    v += ((const float*)resid)[off];
    ((bf16*)Cout)[off] = f2b(v);
  } else {
    v += bias[col] + b2f(((const bf16*)resid)[off]);
    ((float*)Cout)[off] = v;
  }
}

// XOR-swizzle: LDS slot (row, blk16) holds global block (blk16 ^ (row&7)).
// Staging keeps global_load_lds's contiguous lane->LDS mapping; readers XOR too.
//
// GEMM verdict (R0-R8, frozen — the 2-barrier family is exhausted at ~650 TF):
//  - 128x128 single-buffer BK=64 for the K=1024 GEMMs. Probed alternatives all
//    lost: 64KB dbuf (occupancy crash, 96us), BK=32 dbuf (bank conflicts, 83us),
//    64x64 2-phase (total regressed), 256x128@(512,6) (VGPR spill, 290us),
//    256x128@(512,4) (57.4us vs <52.8 for this kernel — R8 cutoff evidence).
//  - 64x64 2-phase counted-vmcnt for the N=1024 GEMMs (only consistent winner).
// R6's exact mix (420us total) restored.

// ---------------- GEMM 128x128 tile; blockIdx.x = M-tile (XCD affinity on A rows) ----------------
template<int EPI>
__global__ __launch_bounds__(256, 2)
void gemm_bt(const bf16* __restrict__ A, const bf16* __restrict__ W,
             const float* __restrict__ bias, const void* __restrict__ resid,
             void* __restrict__ Cout, int M, int N, int K)
{
  __shared__ __align__(16) short Asl[128 * 64];
  __shared__ __align__(16) short Bsl[128 * 64];
  const int tid  = threadIdx.x;
  const int lane = tid & 63;
  const int wv   = tid >> 6;
  const int wm   = wv >> 1, wn = wv & 1;
  const int r16  = lane & 15, q = lane >> 4;
  const int m0   = blockIdx.x * 128;   // x = M-tile: same-A-rows pin to one XCD
  const int n0   = blockIdx.y * 128;

  floatx4 acc[4][4] = {};

  for (int k0 = 0; k0 < K; k0 += 64) {
#pragma unroll
    for (int it = 0; it < 4; ++it) {
      int idx = it * 256 + tid;
      int row = m0 + (idx >> 3);
      int cb  = (((idx & 7) ^ ((idx >> 3) & 7)) << 3);   // swizzled source block
      gload_lds16(A + (size_t)row * K + k0 + cb, &Asl[idx * 8]);
    }
#pragma unroll
    for (int it = 0; it < 4; ++it) {
      int idx = it * 256 + tid;
      int row = n0 + (idx >> 3);
      if (row > N - 1) row = N - 1;
      int cb  = (((idx & 7) ^ ((idx >> 3) & 7)) << 3);
      gload_lds16(W + (size_t)row * K + k0 + cb, &Bsl[idx * 8]);
    }
    __syncthreads();
#pragma unroll
    for (int kk = 0; kk < 64; kk += 32) {
      short8 af[4], bfr[4];
      const int lb = (kk >> 3) + q;                       // logical 16B block 0..7
#pragma unroll
      for (int i = 0; i < 4; ++i) {
        int ar = wm * 64 + i * 16 + r16;
        af[i] = *(const short8*)&Asl[ar * 64 + ((lb ^ (ar & 7)) << 3)];
      }
#pragma unroll
      for (int j = 0; j < 4; ++j) {
        int br = wn * 64 + j * 16 + r16;
        bfr[j] = *(const short8*)&Bsl[br * 64 + ((lb ^ (br & 7)) << 3)];
      }
#pragma unroll
      for (int i = 0; i < 4; ++i)
#pragma unroll
        for (int j = 0; j < 4; ++j)
          acc[i][j] = __builtin_amdgcn_mfma_f32_16x16x32_bf16(af[i], bfr[j], acc[i][j], 0, 0, 0);
    }
    __syncthreads();
  }

#pragma unroll
  for (int i = 0; i < 4; ++i)
#pragma unroll
    for (int j = 0; j < 4; ++j)
#pragma unroll
      for (int r = 0; r < 4; ++r) {
        int row = m0 + wm * 64 + i * 16 + q * 4 + r;
        int col = n0 + wn * 64 + j * 16 + r16;
        if (col < N)
          epi_store<EPI>(acc[i][j][r], (size_t)row * N + col, col, bias, resid, Cout);
      }
}

// ---------------- GEMM 64x64 tile (N=1024 GEMMs): 1024 blocks = 4/CU, 32 KB LDS ----------------
// 2-phase pipeline: stage tile t+1 into buf^1 BEFORE computing tile t; counted
// vmcnt(4) drains only tile t's loads while t+1's stay in flight across the barrier.
template<int EPI>
__global__ __launch_bounds__(256, 4)
void gemm_bt_6464(const bf16* __restrict__ A, const bf16* __restrict__ W,
                  const float* __restrict__ bias, const void* __restrict__ resid,
                  void* __restrict__ Cout, int M, int N, int K)
{
  __shared__ __align__(16) short Asl[2][64 * 64];    // 2 x 8 KB
  __shared__ __align__(16) short Bsl[2][64 * 64];    // 2 x 8 KB
  const int tid  = threadIdx.x;
  const int lane = tid & 63;
  const int wv   = tid >> 6;
  const int wm   = wv >> 1, wn = wv & 1;          // 2x2 wave grid of 32x32 sub-tiles
  const int r16  = lane & 15, q = lane >> 4;
  const int m0   = blockIdx.x * 64;               // x = M-tile: XCD pin on A rows
  const int n0   = blockIdx.y * 64;

  floatx4 acc[2][2] = {};

  auto stage = [&](int b, int k0) {
#pragma unroll
    for (int it = 0; it < 2; ++it) {
      int idx = it * 256 + tid;
      int cb  = (((idx & 7) ^ ((idx >> 3) & 7)) << 3);
      gload_lds16(A + (size_t)(m0 + (idx >> 3)) * K + k0 + cb, &Asl[b][idx * 8]);
    }
#pragma unroll
    for (int it = 0; it < 2; ++it) {
      int idx = it * 256 + tid;
      int cb  = (((idx & 7) ^ ((idx >> 3) & 7)) << 3);
      gload_lds16(W + (size_t)(n0 + (idx >> 3)) * K + k0 + cb, &Bsl[b][idx * 8]);
    }
  };
  auto compute = [&](int b) {
#pragma unroll
    for (int kk = 0; kk < 64; kk += 32) {
      short8 af[2], bfr[2];
      const int lb = (kk >> 3) + q;
#pragma unroll
      for (int i = 0; i < 2; ++i) {
        int ar = wm * 32 + i * 16 + r16;
        af[i] = *(const short8*)&Asl[b][ar * 64 + ((lb ^ (ar & 7)) << 3)];
      }
#pragma unroll
      for (int j = 0; j < 2; ++j) {
        int br = wn * 32 + j * 16 + r16;
        bfr[j] = *(const short8*)&Bsl[b][br * 64 + ((lb ^ (br & 7)) << 3)];
      }
#pragma unroll
      for (int i = 0; i < 2; ++i)
#pragma unroll
        for (int j = 0; j < 2; ++j)
          acc[i][j] = __builtin_amdgcn_mfma_f32_16x16x32_bf16(af[i], bfr[j], acc[i][j], 0, 0, 0);
    }
  };

  stage(0, 0);
  const int nt = K >> 6;
  int cur = 0;
  for (int t = 0; t < nt - 1; ++t) {
    stage(cur ^ 1, (t + 1) << 6);                 // 4 loads/thread in flight
    asm volatile("s_waitcnt vmcnt(4)" ::: "memory");   // drain tile t only
    __builtin_amdgcn_s_barrier();
    compute(cur);
    asm volatile("s_waitcnt lgkmcnt(0)" ::: "memory");
    __builtin_amdgcn_s_barrier();
    cur ^= 1;
  }
  asm volatile("s_waitcnt vmcnt(0)" ::: "memory");
  __builtin_amdgcn_s_barrier();
  compute(cur);

#pragma unroll
  for (int i = 0; i < 2; ++i)
#pragma unroll
    for (int j = 0; j < 2; ++j)
#pragma unroll
      for (int r = 0; r < 4; ++r) {
        int row = m0 + wm * 32 + i * 16 + q * 4 + r;
        int col = n0 + wn * 32 + j * 16 + r16;
        epi_store<EPI>(acc[i][j][r], (size_t)row * N + col, col, bias, resid, Cout);
      }
}

// ---------------- depthwise causal conv (4 tap) + SiLU + softplus(dt) ----------------
// G13: 8-contiguous-channel groups per thread -> 4x short8 tap loads + 8x float4
// weight loads + short8 stores.
__global__ void conv_kernel(const bf16* __restrict__ zx, const float* __restrict__ cw,
                            const float* __restrict__ cb, const float* __restrict__ dtbias,
                            bf16* __restrict__ xbc, bf16* __restrict__ Bb,
                            bf16* __restrict__ Cbb, float* __restrict__ dtb)
{
  int row = blockIdx.x;
  int b = row >> 11, t = row & 2047;
  const size_t rowbase = (size_t)(b * SEQLEN) * DINPROJ + DINNER;
  for (int c8 = threadIdx.x; c8 < CONVDIM / 8; c8 += 256) {
    int c = c8 * 8;
    float acc[8];
    {
      float4 b0 = *(const float4*)(cb + c);
      float4 b1 = *(const float4*)(cb + c + 4);
      acc[0] = b0.x; acc[1] = b0.y; acc[2] = b0.z; acc[3] = b0.w;
      acc[4] = b1.x; acc[5] = b1.y; acc[6] = b1.z; acc[7] = b1.w;
    }
    float4 wj[8];
#pragma unroll
    for (int j = 0; j < 8; ++j) wj[j] = *(const float4*)(cw + (c + j) * 4);
    short8 xv[4];
#pragma unroll
    for (int k = 0; k < 4; ++k) {
      int tt = t + k - 3;
      if (tt >= 0) {
        xv[k] = *(const short8*)(zx + rowbase + (size_t)tt * DINPROJ + c);
#pragma unroll
        for (int j = 0; j < 8; ++j) {
          float wk = (k == 0) ? wj[j].x : (k == 1) ? wj[j].y : (k == 2) ? wj[j].z : wj[j].w;
          acc[j] += s2f(xv[k][j]) * wk;
        }
      }
    }
    short8 outv;
#pragma unroll
    for (int j = 0; j < 8; ++j) {
      float s = acc[j] / (1.f + __expf(-acc[j]));   // SiLU
      outv[j] = f2s(s);
    }
    *(short8*)(xbc + (size_t)row * CONVDIM + c) = outv;
    if (c >= DINNER) {
      if (c < DINNER + DSTATE) *(short8*)(Bb + row * DSTATE + (c - DINNER)) = outv;
      else                     *(short8*)(Cbb + row * DSTATE + (c - DINNER - DSTATE)) = outv;
    }
  }
  if (threadIdx.x < NHEADS) {
    int hh = threadIdx.x;
    float raw = b2f(zx[(size_t)row * DINPROJ + DINNER + CONVDIM + hh]) + dtbias[hh];
    float dt = raw > 20.f ? raw : log1pf(__expf(raw));   // softplus
    dtb[row * NHEADS + hh] = dt;
  }
}

// ---------------- wave inclusive prefix sum helper ----------------
__device__ __forceinline__ float wave_incl_prefix(float a, int lane) {
#pragma unroll
  for (int off = 1; off < 64; off <<= 1) {
    float o = __shfl_up(a, off);
    if (lane >= off) a += o;
  }
  return a;
}

// ---------------- SSD phase A: chunk end-state S = Xw^T @ B, decay P ----------------
__global__ __launch_bounds__(64)
void chunk_state_kernel(const bf16* __restrict__ xbc, const bf16* __restrict__ Bb,
                        const float* __restrict__ dtb, const float* __restrict__ A_log,
                        float* __restrict__ Sbuf, float* __restrict__ Pbuf)
{
  const int blk = blockIdx.x;
  const int c = blk & 31, h = (blk >> 5) & 31, b = blk >> 10;
  const int bh = b * 32 + h;
  const int lane = threadIdx.x;              // = s (timestep within chunk)
  const int row = b * SEQLEN + c * 64 + lane;
  const float Ah = -__expf(A_log[h]);

  float dts = dtb[row * NHEADS + h];
  float E = wave_incl_prefix(dts * Ah, lane);
  float EQ = __shfl(E, 63);
  float w = __expf(EQ - E) * dts;
  if (lane == 63) Pbuf[bh * NCHUNK + c] = __expf(EQ);

  __shared__ __align__(16) short XwT[64 * 72];   // [p][s] pad 72
  __shared__ __align__(16) short BT[64 * 72];    // [n][s] pad 72

  const bf16* xrow = xbc + (size_t)row * CONVDIM + h * 64;
  const bf16* brow = Bb + (size_t)row * DSTATE;
#pragma unroll
  for (int i = 0; i < 8; ++i) {
    short8 xv = *(const short8*)(xrow + i * 8);
    short8 bv = *(const short8*)(brow + i * 8);
#pragma unroll
    for (int j = 0; j < 8; ++j) {
      XwT[(i * 8 + j) * 72 + lane] = f2s(w * s2f(xv[j]));
      BT[(i * 8 + j) * 72 + lane]  = bv[j];
    }
  }
  __syncthreads();

  const int r16 = lane & 15, q = lane >> 4;
  floatx4 acc[4][4] = {};
#pragma unroll
  for (int kk = 0; kk < 64; kk += 32) {
    short8 af[4], bfr[4];
#pragma unroll
    for (int i = 0; i < 4; ++i) af[i]  = *(const short8*)&XwT[(i * 16 + r16) * 72 + kk + q * 8];
#pragma unroll
    for (int j = 0; j < 4; ++j) bfr[j] = *(const short8*)&BT[(j * 16 + r16) * 72 + kk + q * 8];
#pragma unroll
    for (int i = 0; i < 4; ++i)
#pragma unroll
      for (int j = 0; j < 4; ++j)
        acc[i][j] = __builtin_amdgcn_mfma_f32_16x16x32_bf16(af[i], bfr[j], acc[i][j], 0, 0, 0);
  }
  float* Sout = Sbuf + (size_t)(bh * NCHUNK + c) * 4096;
#pragma unroll
  for (int i = 0; i < 4; ++i)
#pragma unroll
    for (int j = 0; j < 4; ++j)
#pragma unroll
      for (int r = 0; r < 4; ++r)
        Sout[(i * 16 + q * 4 + r) * 64 + (j * 16 + r16)] = acc[i][j][r];
}

// ---------------- SSD phase B: serial chunk combine (scalar decay) ----------------
// R8 fix: was 256 blocks x 64 thr = 1 wave/CU (G11 violation — serial 32-step scan
// with zero latency hiding). Now 64 bh x 16 slabs = 1024 blocks (4 waves/CU),
// thread owns 4 contiguous floats (float4 read / uint2 bf16 write per step).
__global__ __launch_bounds__(64)
void combine_kernel(const float* __restrict__ Sbuf, const float* __restrict__ Pbuf,
                    bf16* __restrict__ HinB)
{
  const int bh = blockIdx.x >> 4, slab = blockIdx.x & 15;
  const int base = slab * 256 + threadIdx.x * 4;
  float h0 = 0.f, h1 = 0.f, h2 = 0.f, h3 = 0.f;
  const float* Pb = Pbuf + bh * NCHUNK;
  for (int c = 0; c < NCHUNK; ++c) {
    size_t off = (size_t)(bh * NCHUNK + c) * 4096 + base;
    union { short s[4]; uint2 q; } pk;
    pk.s[0] = f2s(h0); pk.s[1] = f2s(h1); pk.s[2] = f2s(h2); pk.s[3] = f2s(h3);
    *(uint2*)(HinB + off) = pk.q;
    float P = Pb[c];
    float4 s = *(const float4*)(Sbuf + off);
    h0 = h0 * P + s.x;
    h1 = h1 * P + s.y;
    h2 = h2 * P + s.z;
    h3 = h3 * P + s.w;
  }
}

// ---------------- SSD phase C: Y = (mask ⊙ C B^T) @ Xdt + (e^E C) @ Hin^T + D x ----------------
__global__ __launch_bounds__(64)
void y_kernel(const bf16* __restrict__ xbc, const bf16* __restrict__ Bb,
              const bf16* __restrict__ Cbb, const float* __restrict__ dtb,
              const bf16* __restrict__ HinB, const float* __restrict__ A_log,
              const float* __restrict__ Dp, bf16* __restrict__ yout)
{
  const int blk = blockIdx.x;
  const int c = blk & 31, h = (blk >> 5) & 31, b = blk >> 10;
  const int bh = b * 32 + h;
  const int lane = threadIdx.x;              // = s for the builds
  const int row0 = b * SEQLEN + c * 64;
  const int row = row0 + lane;
  const float Ah = -__expf(A_log[h]);
  const float Dh = Dp[h];

  __shared__ __align__(16) short XdT[64 * 72];  // [p][s]
  __shared__ __align__(16) short Msh[64 * 72];  // [t][s]
  __shared__ float Esh[64];

  float dts = dtb[row * NHEADS + h];
  float E = wave_incl_prefix(dts * Ah, lane);
  Esh[lane] = E;

  const bf16* xrow = xbc + (size_t)row * CONVDIM + h * 64;
#pragma unroll
  for (int i = 0; i < 8; ++i) {
    short8 xv = *(const short8*)(xrow + i * 8);
#pragma unroll
    for (int j = 0; j < 8; ++j)
      XdT[(i * 8 + j) * 72 + lane] = f2s(dts * s2f(xv[j]));
  }
  __syncthreads();

  const int r16 = lane & 15, q = lane >> 4;

  // G = C @ B^T  (t x s)
  floatx4 accg[4][4] = {};
#pragma unroll
  for (int kk = 0; kk < 64; kk += 32) {
    short8 af[4], bfr[4];
#pragma unroll
    for (int i = 0; i < 4; ++i)
      af[i]  = *(const short8*)(Cbb + (size_t)(row0 + i * 16 + r16) * DSTATE + kk + q * 8);
#pragma unroll
    for (int j = 0; j < 4; ++j)
      bfr[j] = *(const short8*)(Bb + (size_t)(row0 + j * 16 + r16) * DSTATE + kk + q * 8);
#pragma unroll
    for (int i = 0; i < 4; ++i)
#pragma unroll
      for (int j = 0; j < 4; ++j)
        accg[i][j] = __builtin_amdgcn_mfma_f32_16x16x32_bf16(af[i], bfr[j], accg[i][j], 0, 0, 0);
  }
  // causal decay mask -> Msh (bf16, A-operand layout for next MFMA)
#pragma unroll
  for (int i = 0; i < 4; ++i)
#pragma unroll
    for (int j = 0; j < 4; ++j)
#pragma unroll
      for (int r = 0; r < 4; ++r) {
        int t = i * 16 + q * 4 + r;
        int s = j * 16 + r16;
        float v = (s <= t) ? __expf(Esh[t] - Esh[s]) * accg[i][j][r] : 0.f;
        Msh[t * 72 + s] = f2s(v);
      }
  __syncthreads();

  floatx4 acc[4][4] = {};
  // Y_intra = M @ Xdt   (t x p)
#pragma unroll
  for (int kk = 0; kk < 64; kk += 32) {
    short8 af[4], bfr[4];
#pragma unroll
    for (int i = 0; i < 4; ++i) af[i]  = *(const short8*)&Msh[(i * 16 + r16) * 72 + kk + q * 8];
#pragma unroll
    for (int j = 0; j < 4; ++j) bfr[j] = *(const short8*)&XdT[(j * 16 + r16) * 72 + kk + q * 8];
#pragma unroll
    for (int i = 0; i < 4; ++i)
#pragma unroll
      for (int j = 0; j < 4; ++j)
        acc[i][j] = __builtin_amdgcn_mfma_f32_16x16x32_bf16(af[i], bfr[j], acc[i][j], 0, 0, 0);
  }
  // Y_inter = (e^{E_t} C) @ Hin^T   (t x p)
  float ei[4];
#pragma unroll
  for (int i = 0; i < 4; ++i) ei[i] = __expf(Esh[i * 16 + r16]);
  const bf16* hinp = HinB + (size_t)(bh * NCHUNK + c) * 4096;
#pragma unroll
  for (int kk = 0; kk < 64; kk += 32) {
    short8 af[4], bfr[4];
#pragma unroll
    for (int i = 0; i < 4; ++i) {
      short8 cv = *(const short8*)(Cbb + (size_t)(row0 + i * 16 + r16) * DSTATE + kk + q * 8);
#pragma unroll
      for (int jj = 0; jj < 8; ++jj) af[i][jj] = f2s(ei[i] * s2f(cv[jj]));
    }
#pragma unroll
    for (int j = 0; j < 4; ++j)
      bfr[j] = *(const short8*)(hinp + (j * 16 + r16) * 64 + kk + q * 8);
#pragma unroll
    for (int i = 0; i < 4; ++i)
#pragma unroll
      for (int j = 0; j < 4; ++j)
        acc[i][j] = __builtin_amdgcn_mfma_f32_16x16x32_bf16(af[i], bfr[j], acc[i][j], 0, 0, 0);
  }
  // epilogue: + D * x, store bf16
#pragma unroll
  for (int i = 0; i < 4; ++i)
#pragma unroll
    for (int j = 0; j < 4; ++j)
#pragma unroll
      for (int r = 0; r < 4; ++r) {
        int t = i * 16 + q * 4 + r;
        int p = j * 16 + r16;
        int g = row0 + t;
        float y = acc[i][j][r] + Dh * b2f(xbc[(size_t)g * CONVDIM + h * 64 + p]);
        yout[(size_t)g * DINNER + h * 64 + p] = f2b(y);
      }
}

// ---------------- gate (y * silu(z)) + RMSNorm ----------------
// G13: thread t owns cols 8t..8t+7 -> 2x short8 loads, short8 store.
__global__ void gate_rms_kernel(const bf16* __restrict__ y, const bf16* __restrict__ zx,
                                const float* __restrict__ nw, bf16* __restrict__ yn)
{
  int row = blockIdx.x, tid = threadIdx.x;
  int c0 = tid * 8;
  short8 zv = *(const short8*)(zx + (size_t)row * DINPROJ + c0);
  short8 yv = *(const short8*)(y  + (size_t)row * DINNER  + c0);
  float v[8]; float ss = 0.f, dummy = 0.f;
#pragma unroll
  for (int j = 0; j < 8; ++j) {
    float z = s2f(zv[j]);
    float g = z / (1.f + __expf(-z));
    float val = s2f(yv[j]) * g;
    v[j] = val; ss += val * val;
  }
  block_reduce_2(ss, dummy);
  float rs = rsqrtf(ss * (1.f / DINNER) + 1e-5f);
  float4 w0 = *(const float4*)(nw + c0);
  float4 w1 = *(const float4*)(nw + c0 + 4);
  short8 outv;
  outv[0] = f2s(v[0] * rs * w0.x); outv[1] = f2s(v[1] * rs * w0.y);
  outv[2] = f2s(v[2] * rs * w0.z); outv[3] = f2s(v[3] * rs * w0.w);
  outv[4] = f2s(v[4] * rs * w1.x); outv[5] = f2s(v[5] * rs * w1.y);
  outv[6] = f2s(v[6] * rs * w1.z); outv[7] = f2s(v[7] * rs * w1.w);
  *(short8*)(yn + (size_t)row * DINNER + c0) = outv;
}

extern "C" void kernel_launch(void* const* d_in, const int* in_sizes, int n_in,
                              void* d_out, int out_size, void* d_ws, size_t ws_size,
                              hipStream_t stream)
{
  const float* x         = (const float*)d_in[0];
  const float* ln1_w     = (const float*)d_in[1];
  const float* ln1_b     = (const float*)d_in[2];
  const float* in_proj_w = (const float*)d_in[3];
  const float* conv_w    = (const float*)d_in[4];
  const float* conv_b    = (const float*)d_in[5];
  const float* dt_bias   = (const float*)d_in[6];
  const float* A_log     = (const float*)d_in[7];
  const float* Dp        = (const float*)d_in[8];
  const float* norm_w    = (const float*)d_in[9];
  const float* out_proj_w= (const float*)d_in[10];
  const float* ln2_w     = (const float*)d_in[11];
  const float* ln2_b     = (const float*)d_in[12];
  const float* mlp_w1    = (const float*)d_in[13];
  const float* mlp_b1    = (const float*)d_in[14];
  const float* mlp_w2    = (const float*)d_in[15];
  const float* mlp_b2    = (const float*)d_in[16];

  char* ws = (char*)d_ws;
  bf16*  zx   = (bf16*)(ws + 0);            // 34,865,152
  bf16*  h1   = (bf16*)(ws + 34865152);     //  8,388,608
  bf16*  xbc  = (bf16*)(ws + 43253760);     // 17,825,792 (reused as w2b)
  bf16*  Bb   = (bf16*)(ws + 61079552);     //    524,288
  bf16*  Cbb  = (bf16*)(ws + 61603840);     //    524,288
  float* dtb  = (float*)(ws + 62128128);    //    524,288
  float* Pbuf = (float*)(ws + 62652416);    //      8,192
  float* Sbuf = (float*)(ws + 62660608);    // 33,554,432 fp32 (dead after combine)
  bf16*  yw   = (bf16*)(ws + 62660608);     // 16,777,216 bf16 (alias Sbuf lower; Sbuf dead)
  bf16*  x2   = (bf16*)(ws + 79437824);     //  8,388,608 bf16 (alias Sbuf upper; yw-disjoint)
  bf16*  HinB = (bf16*)(ws + 96215040);     //  8,388,608
  bf16*  yn   = (bf16*)(ws + 96215040);     // 16,777,216 (overlays HinB; HinB dead after y_kernel)
  bf16*  wip  = (bf16*)(ws + 112992256);    //  8,716,288 (reused as w1b)
  bf16*  wop  = (bf16*)(ws + 121708544);    //  4,194,304 -> end 125,902,848
  bf16*  h2n  = h1;
  bf16*  mid  = zx;
  bf16*  w1b  = wip;
  bf16*  w2b  = xbc;

  // 0a. convert in_proj_w to bf16
  cvt_kernel<<<(4256 * 1024 / 4 + 255) / 256, 256, 0, stream>>>(in_proj_w, wip, 4256 * 1024 / 4);
  // 1. LN1
  ln_kernel<float><<<ROWS, 256, 0, stream>>>(x, ln1_w, ln1_b, h1);
  // 2. in_proj   [grid x = M-tiles (32), y = N-tiles (34)]
  gemm_bt<0><<<dim3(32, 34), 256, 0, stream>>>(h1, wip, nullptr, nullptr, zx,
                                               ROWS, DINPROJ, DMODEL);
  // 0b. convert mlp_w1 (into wip region) and out_proj_w
  cvt_kernel<<<(4096 * 1024 / 4 + 255) / 256, 256, 0, stream>>>(mlp_w1, w1b, 4096 * 1024 / 4);
  cvt_kernel<<<(1024 * 2048 / 4 + 255) / 256, 256, 0, stream>>>(out_proj_w, wop, 1024 * 2048 / 4);
  // 3. conv + SiLU + softplus(dt)
  conv_kernel<<<ROWS, 256, 0, stream>>>(zx, conv_w, conv_b, dt_bias, xbc, Bb, Cbb, dtb);
  // 4a. SSD phase A: per-chunk end states
  chunk_state_kernel<<<2048, 64, 0, stream>>>(xbc, Bb, dtb, A_log, Sbuf, Pbuf);
  // 4b. SSD phase B: combine chunk states   [1024 blocks = 4 waves/CU]
  combine_kernel<<<1024, 64, 0, stream>>>(Sbuf, Pbuf, HinB);
  // 4c. SSD phase C: outputs (bf16)
  y_kernel<<<2048, 64, 0, stream>>>(xbc, Bb, Cbb, dtb, HinB, A_log, Dp, yw);
  // 0c. convert mlp_w2 (xbc region dead now)
  cvt_kernel<<<(1024 * 4096 / 4 + 255) / 256, 256, 0, stream>>>(mlp_w2, w2b, 1024 * 4096 / 4);
  // 5. gate + RMSNorm
  gate_rms_kernel<<<ROWS, 256, 0, stream>>>(yw, zx, norm_w, yn);
  // 6. out_proj + residual(x, fp32) -> x2 (bf16)   [64x64 2-phase, 1024 blocks]
  gemm_bt_6464<2><<<dim3(64, 16), 256, 0, stream>>>(yn, wop, nullptr, x, (void*)x2,
                                                    ROWS, DMODEL, DINNER);
  // 7. LN2 (bf16 in)
  ln_kernel<bf16><<<ROWS, 256, 0, stream>>>(x2, ln2_w, ln2_b, h2n);
  // 8. mlp1 + bias + GELU   [grid x = M-tiles (32), y = N-tiles (32)]
  gemm_bt<1><<<dim3(32, 32), 256, 0, stream>>>(h2n, w1b, mlp_b1, nullptr, mid,
                                               ROWS, 4 * DMODEL, DMODEL);
  // 9. mlp2 + bias + residual(x2, bf16) -> out (fp32)   [64x64 2-phase, 1024 blocks]
  gemm_bt_6464<3><<<dim3(64, 16), 256, 0, stream>>>(mid, w2b, mlp_b2, x2, d_out,
                                                    ROWS, DMODEL, 4 * DMODEL);
}